// Round 1
// baseline (370.617 us; speedup 1.0000x reference)
//
#include <hip/hip_runtime.h>
#include <hip/hip_bf16.h>

// SelfAttention B=2,N=4096,E=512,H=8,D=64 — Round 11:
// R10 + (a) attn LDS 33280->32768 (Lred aliased into Vs region, +1 barrier)
//          -> 5 blocks/CU instead of 4 (occupancy was the limiter: all pipes ~45-60%)
//      (b) XCD-aware block swizzle in gemm_mfma_kernel (A-panel L2 locality).

#define ROWS 8192
#define EMB  512
#define SEQ  4096
#define HEADS 8
#define HD   64
#define SPLIT 2
#define QSCALE 0.18033688011112042f   // 0.125 * log2(e)

typedef __attribute__((ext_vector_type(8))) short bf16x8;
typedef __attribute__((ext_vector_type(4))) short bf16x4;
typedef __attribute__((ext_vector_type(4))) float f32x4;

#define MFMA_K16(A, B, C) __builtin_amdgcn_mfma_f32_16x16x16bf16_1k(A, B, C, 0, 0, 0)

__device__ __forceinline__ float bf16_to_f(unsigned short u) {
    union { unsigned int i; float f; } v; v.i = ((unsigned int)u) << 16; return v.f;
}
__device__ __forceinline__ unsigned short f_to_bf16(float f) {
    union { __hip_bfloat16 h; unsigned short u; } v; v.h = __float2bfloat16(f); return v.u;
}
__device__ __forceinline__ unsigned int pack_bf16_trunc(float a, float b) {
    return (__float_as_uint(a) >> 16) | (__float_as_uint(b) & 0xFFFF0000u);
}
__device__ __forceinline__ void load_lds16(const void* g, void* l) {
    __builtin_amdgcn_global_load_lds(
        (const __attribute__((address_space(1))) void*)g,
        (__attribute__((address_space(3))) void*)l, 16, 0, 0);
}

// ---- dtype detection (fp32 buffers: random halfwords -> wild exponents)
__global__ void detect_kernel(const void* x, int* flag) {
    const unsigned short* p = (const unsigned short*)x;
    int t = threadIdx.x;
    int cnt = 0;
    for (int i = 0; i < 4; ++i) {
        unsigned short u = p[t * 4 + i];
        int e = (u >> 7) & 0xFF;
        if (e >= 140) cnt++;
    }
    for (int off = 32; off > 0; off >>= 1) cnt += __shfl_down(cnt, off, 64);
    if (t == 0) *flag = (cnt > 16) ? 1 : 0;   // 1 = fp32, 0 = bf16
}

// ---- only needed when input fp32: x -> x_f (fp32 copy) + xb (bf16)
__global__ __launch_bounds__(256) void conv_x_kernel(const void* __restrict__ x,
        float* __restrict__ xf, unsigned short* __restrict__ xb, const int* __restrict__ flag) {
    if (*flag == 0) return;
    int i = (blockIdx.x * 256 + threadIdx.x) * 4;
    float4 v = *(const float4*)((const float*)x + i);
    *(float4*)(xf + i) = v;
    ushort4 u = { f_to_bf16(v.x), f_to_bf16(v.y), f_to_bf16(v.z), f_to_bf16(v.w) };
    *(ushort4*)(xb + i) = u;
}

// ---- weights [K][N] -> Wt bf16 [mat*512 + n][k]
__global__ __launch_bounds__(256) void conv_wt_kernel(
        const void* W0, const void* W1, const void* W2, const void* W3,
        unsigned short* __restrict__ Wt, const int* __restrict__ flag) {
    __shared__ float T[64][65];
    int tid = threadIdx.x;
    int kt = blockIdx.x, nt = blockIdx.y, mat = blockIdx.z;
    const void* src = (mat == 0) ? W0 : (mat == 1) ? W1 : (mat == 2) ? W2 : W3;
    int fp32 = *flag;
    for (int ii = 0; ii < 4; ++ii) {
        int idx = tid + ii * 256;
        int i = idx >> 4, j = (idx & 15) * 4;
        size_t g = (size_t)(kt * 64 + i) * 512 + nt * 64 + j;
        if (fp32) {
            float4 v = *(const float4*)((const float*)src + g);
            T[i][j] = v.x; T[i][j+1] = v.y; T[i][j+2] = v.z; T[i][j+3] = v.w;
        } else {
            ushort4 u = *(const ushort4*)((const unsigned short*)src + g);
            T[i][j] = bf16_to_f(u.x); T[i][j+1] = bf16_to_f(u.y);
            T[i][j+2] = bf16_to_f(u.z); T[i][j+3] = bf16_to_f(u.w);
        }
    }
    __syncthreads();
    for (int ii = 0; ii < 2; ++ii) {
        int idx = tid + ii * 256;
        int j = idx >> 3, ch = idx & 7;
        unsigned short pk[8];
        for (int t = 0; t < 8; ++t) pk[t] = f_to_bf16(T[ch * 8 + t][j]);
        *(bf16x8*)&Wt[(size_t)(mat * 512 + nt * 64 + j) * 512 + kt * 64 + ch * 8] = *(bf16x8*)pk;
    }
}

// ---- 6 small vectors -> bias_all fp32 [6][512]: bq,bk,bv,bo,gamma,beta
__global__ __launch_bounds__(256) void conv_small_kernel(
        const void* b0, const void* b1, const void* b2, const void* b3,
        const void* b4, const void* b5, float* __restrict__ dst, const int* __restrict__ flag) {
    int idx = blockIdx.x * 256 + threadIdx.x;
    int mat = idx >> 9, off = idx & 511;
    const void* src = (mat == 0) ? b0 : (mat == 1) ? b1 : (mat == 2) ? b2 :
                      (mat == 3) ? b3 : (mat == 4) ? b4 : b5;
    float v;
    if (*flag) v = ((const float*)src)[off];
    else       v = bf16_to_f(((const unsigned short*)src)[off]);
    dst[idx] = v;
}

// ---- MFMA GEMM: C = A * Bt^T + bias, 128x128x64 tiles. A chosen per flag.
// If VtOut != null, cols >= 1024 (V block of fused QKV) are written TRANSPOSED
// to VtOut[bh][d][seq] (bf16) instead of to C.
// R11: XCD-aware block swizzle (grid %8==0 in both uses) — consecutive
// dispatch ids round-robin XCDs; remap so each XCD owns a contiguous
// m-row chunk -> A-panels become L2-resident per XCD.
template <typename OutT>
__global__ __launch_bounds__(256) void gemm_mfma_kernel(
        const unsigned short* __restrict__ A_conv, const unsigned short* __restrict__ A_raw,
        const int* __restrict__ flag,
        const unsigned short* __restrict__ Bt,
        const float* __restrict__ bias, OutT* __restrict__ C, int ldc, int scale_cols,
        unsigned short* __restrict__ VtOut) {
    __shared__ unsigned short At[128 * 64];
    __shared__ unsigned short Bs[128 * 64];
    const unsigned short* A = (*flag) ? A_conv : A_raw;
    int tid = threadIdx.x;
    int wave = tid >> 6, lane = tid & 63;
    int l15 = lane & 15, quad = lane >> 4;

    int lin = blockIdx.x + gridDim.x * blockIdx.y;
    int nwg = gridDim.x * gridDim.y;
    int bx, by;
    if (nwg & 7) { bx = blockIdx.x; by = blockIdx.y; }
    else {
        int t = (lin & 7) * (nwg >> 3) + (lin >> 3);
        bx = t % gridDim.x; by = t / gridDim.x;
    }
    int m0 = by * 128, n0 = bx * 128;
    int wm = (wave & 1) * 64, wn = (wave >> 1) * 64;

    int rt = wave * 32 + (lane >> 3);
    int ch = (lane & 7) ^ ((lane >> 3) & 7);
    const unsigned short* ag = A  + (size_t)(m0 + rt) * 512 + ch * 8;
    const unsigned short* bg = Bt + (size_t)(n0 + rt) * 512 + ch * 8;

    f32x4 acc[4][4];
    for (int i = 0; i < 4; ++i) for (int j = 0; j < 4; ++j) acc[i][j] = (f32x4){0.f,0.f,0.f,0.f};

    for (int k0 = 0; k0 < 512; k0 += 64) {
        __syncthreads();
        #pragma unroll
        for (int j = 0; j < 4; ++j) {
            load_lds16(ag + (size_t)(j * 8) * 512 + k0, &At[(wave * 32 + j * 8) * 64]);
            load_lds16(bg + (size_t)(j * 8) * 512 + k0, &Bs[(wave * 32 + j * 8) * 64]);
        }
        __syncthreads();
        #pragma unroll
        for (int ks = 0; ks < 2; ++ks) {
            bf16x8 a[4], b[4];
            #pragma unroll
            for (int f = 0; f < 4; ++f) {
                int pc = ((ks * 4 + quad) ^ (l15 & 7)) * 8;
                a[f] = *(const bf16x8*)&At[(wm + f * 16 + l15) * 64 + pc];
                b[f] = *(const bf16x8*)&Bs[(wn + f * 16 + l15) * 64 + pc];
            }
            #pragma unroll
            for (int fm = 0; fm < 4; ++fm)
                #pragma unroll
                for (int fn = 0; fn < 4; ++fn)
                    acc[fm][fn] = __builtin_amdgcn_mfma_f32_16x16x32_bf16(a[fm], b[fn], acc[fm][fn], 0, 0, 0);
        }
    }
    #pragma unroll
    for (int fm = 0; fm < 4; ++fm) {
        #pragma unroll
        for (int fn = 0; fn < 4; ++fn) {
            int col = n0 + wn + fn * 16 + l15;
            float bia = bias[col];
            float sc = (col < scale_cols) ? QSCALE : 1.f;
            int rowbase = m0 + wm + fm * 16 + quad * 4;
            float v0 = (acc[fm][fn][0] + bia) * sc;
            float v1 = (acc[fm][fn][1] + bia) * sc;
            float v2 = (acc[fm][fn][2] + bia) * sc;
            float v3 = (acc[fm][fn][3] + bia) * sc;
            if (VtOut && col >= 1024) {
                int hd = col - 1024;
                int bh = (rowbase >> 12) * 8 + (hd >> 6);
                int d  = hd & 63;
                ushort4 pk = { f_to_bf16(v0), f_to_bf16(v1), f_to_bf16(v2), f_to_bf16(v3) };
                *(ushort4*)&VtOut[((size_t)(bh * 64 + d)) * SEQ + (rowbase & 4095)] = pk;
            } else {
                if constexpr (sizeof(OutT) == 2) {
                    C[(size_t)(rowbase + 0) * ldc + col] = (OutT)f_to_bf16(v0);
                    C[(size_t)(rowbase + 1) * ldc + col] = (OutT)f_to_bf16(v1);
                    C[(size_t)(rowbase + 2) * ldc + col] = (OutT)f_to_bf16(v2);
                    C[(size_t)(rowbase + 3) * ldc + col] = (OutT)f_to_bf16(v3);
                } else {
                    C[(size_t)(rowbase + 0) * ldc + col] = v0;
                    C[(size_t)(rowbase + 1) * ldc + col] = v1;
                    C[(size_t)(rowbase + 2) * ldc + col] = v2;
                    C[(size_t)(rowbase + 3) * ldc + col] = v3;
                }
            }
        }
    }
}

// ---- MFMA flash attention: LDS-staged K/V + register P. Block = 64 q, 4 waves in
// 2q x 2k split: wave = (qh = wave>>1)*32 q-rows x (kh = wave&1)*64 kcols of each
// 128-k tile. S^T = K·Q^T (swapped operands) -> exp2 -> bf16x4 A-frag -> K16 PV,
// no Ps LDS. Split-K=2, XCD swizzle. Epilogue: cross-kh O/l reduction via LDS.
// R11: LDS = exactly 32768 (Lred aliased at +16384, past the 16KB Ored region)
// -> 5 blocks/CU (was 4 at 33280). One extra barrier before Lred store since it
// now aliases live Vs.
__global__ __launch_bounds__(256, 5) void attn_kernel(
        const unsigned short* __restrict__ QKV, const unsigned short* __restrict__ Vt,
        float* __restrict__ Opart, float* __restrict__ Lpart) {
    __shared__ __align__(16) unsigned char smem[32768];
    unsigned short* Ks = (unsigned short*)smem;              // [128 krow][64 d] swizzled
    unsigned short* Vs = (unsigned short*)(smem + 16384);    // [64 d][128 krow] swizzled
    float* Ored = (float*)smem;                              // epilogue [4 w][16 q][64 d] (16KB)
    float* Lred = (float*)(smem + 16384);                    // epilogue [4 w][2 t][16 q] (512B)

    int tid = threadIdx.x;
    int wave = tid >> 6, lane = tid & 63;
    int l15 = lane & 15, quad = lane >> 4;
    int qh = wave >> 1, kh = wave & 1;
    // grid 2048 = 8 xcd * 256 slots; grp = xcd + 8*(slot>>6); qt = slot&63
    int lin = blockIdx.x;
    int xcd = lin & 7, slot = lin >> 3;
    int grp = xcd + 8 * (slot >> 6);
    int qt = slot & 63;
    int h = grp & 7, b = (grp >> 3) & 1, s = grp >> 4;
    int bh = b * HEADS + h;
    int k0base = s * (SEQ / SPLIT);
    size_t qrow0 = (size_t)b * SEQ + qt * 64;

    // Q B-frags (n = q = l15, k = d): rows qh*32 + t*16 + l15. Pre-scaled by QSCALE.
    bf16x8 aq[2][2];
    #pragma unroll
    for (int t = 0; t < 2; ++t) {
        const unsigned short* qp = &QKV[(qrow0 + qh * 32 + t * 16 + l15) * 1536 + h * 64];
        aq[t][0] = *(const bf16x8*)&qp[quad * 8];
        aq[t][1] = *(const bf16x8*)&qp[32 + quad * 8];
    }
    f32x4 o[2][4];     // [t][db]: O[q = qh*32+t*16+quad*4+r][d = db*16+l15], partial over kh
    #pragma unroll
    for (int t = 0; t < 2; ++t)
        #pragma unroll
        for (int db = 0; db < 4; ++db) o[t][db] = (f32x4){0.f, 0.f, 0.f, 0.f};
    float lp[2] = {0.f, 0.f};   // per-lane: q = l15, summed over this lane's kcols

    // staging pointers (identical pattern to R9)
    int krt = wave * 32 + (lane >> 3);
    int kch = (lane & 7) ^ ((lane >> 3) & 7);
    const unsigned short* kg =
        &QKV[((size_t)b * SEQ + k0base + krt) * 1536 + 512 + h * 64 + kch * 8];

    for (int kt = 0; kt < SEQ / SPLIT / 128; ++kt) {
        __syncthreads();
        #pragma unroll
        for (int j = 0; j < 4; ++j) {
            load_lds16(kg + (size_t)(kt * 128 + j * 8) * 1536, &Ks[(wave * 32 + j * 8) * 64]);
            int d = wave * 16 + j * 4 + quad;
            int vch = l15 ^ (d & 7);
            load_lds16(&Vt[((size_t)bh * 64 + d) * SEQ + k0base + kt * 128 + vch * 8],
                       &Vs[(wave * 16 + j * 4) * 128]);
        }
        __syncthreads();

        #pragma unroll
        for (int nb = 0; nb < 4; ++nb) {
            int kc = kh * 64 + nb * 16;              // wave's kcol tile base in 128-tile
            // K A-frag (m = kcol = l15 within tile, k = d): rows kc + l15
            int krow = kc + l15;
            int key = krow & 7;
            bf16x8 kA0 = *(const bf16x8*)&Ks[krow * 64 + (quad ^ key) * 8];
            bf16x8 kA1 = *(const bf16x8*)&Ks[krow * 64 + ((4 + quad) ^ key) * 8];
            // V B-frags (k = kcol = quad*4+j, n = d = db*16+l15): 8B reads
            bf16x4 bv[4];
            #pragma unroll
            for (int db = 0; db < 4; ++db) {
                int d = db * 16 + l15;
                int c16 = (kc >> 3) + (quad >> 1);   // 16B chunk index
                int sub = (quad & 1) * 4;
                bv[db] = *(const bf16x4*)&Vs[d * 128 + ((c16 ^ (d & 7)) * 8) + sub];
            }
            #pragma unroll
            for (int t = 0; t < 2; ++t) {
                f32x4 sv = {0.f, 0.f, 0.f, 0.f};
                sv = __builtin_amdgcn_mfma_f32_16x16x32_bf16(kA0, aq[t][0], sv, 0, 0, 0);
                sv = __builtin_amdgcn_mfma_f32_16x16x32_bf16(kA1, aq[t][1], sv, 0, 0, 0);
                float p0 = __builtin_amdgcn_exp2f(sv[0]);
                float p1 = __builtin_amdgcn_exp2f(sv[1]);
                float p2 = __builtin_amdgcn_exp2f(sv[2]);
                float p3 = __builtin_amdgcn_exp2f(sv[3]);
                lp[t] += (p0 + p1) + (p2 + p3);
                union { unsigned int u[2]; bf16x4 v; } ap;
                ap.u[0] = pack_bf16_trunc(p0, p1);
                ap.u[1] = pack_bf16_trunc(p2, p3);
                #pragma unroll
                for (int db = 0; db < 4; ++db)
                    o[t][db] = MFMA_K16(ap.v, bv[db], o[t][db]);
            }
        }
    }

    // ---- epilogue: l over quads (shfl); O/l over kh pairs via LDS (aliases Ks/Vs)
    // Lred aliases Vs now -> barrier before storing (all waves must be done reading Vs).
    __syncthreads();
    #pragma unroll
    for (int t = 0; t < 2; ++t) {
        float v = lp[t];
        v += __shfl_xor(v, 16, 64);
        v += __shfl_xor(v, 32, 64);
        if (quad == 0) Lred[(wave * 2 + t) * 16 + l15] = v;
    }
    __syncthreads();
    float* myO = Ored + wave * (16 * 64);
    #pragma unroll
    for (int t = 0; t < 2; ++t) {
        #pragma unroll
        for (int db = 0; db < 4; ++db)
            #pragma unroll
            for (int r = 0; r < 4; ++r)
                myO[(quad * 4 + r) * 64 + db * 16 + l15] = o[t][db][r];
        __syncthreads();
        {
            int q_l = tid >> 3;              // 0..31
            int dg = tid & 7;
            int qh2 = q_l >> 4, qq = q_l & 15;
            const float* r0 = Ored + (qh2 * 2 + 0) * (16 * 64) + qq * 64 + dg * 8;
            const float* r1 = Ored + (qh2 * 2 + 1) * (16 * 64) + qq * 64 + dg * 8;
            float4 a0 = *(const float4*)&r0[0];
            float4 a1 = *(const float4*)&r0[4];
            float4 c0 = *(const float4*)&r1[0];
            float4 c1 = *(const float4*)&r1[4];
            float4 o0 = { a0.x + c0.x, a0.y + c0.y, a0.z + c0.z, a0.w + c0.w };
            float4 o1 = { a1.x + c1.x, a1.y + c1.y, a1.z + c1.z, a1.w + c1.w };
            size_t row = qrow0 + qh2 * 32 + t * 16 + qq;
            float* dst = &Opart[((size_t)s * ROWS + row) * EMB + h * 64 + dg * 8];
            *(float4*)&dst[0] = o0;
            *(float4*)&dst[4] = o1;
            if (dg == 0) {
                float lt = Lred[((qh2 * 2 + 0) * 2 + t) * 16 + qq] +
                           Lred[((qh2 * 2 + 1) * 2 + t) * 16 + qq];
                Lpart[((size_t)s * ROWS + row) * 8 + h] = lt;
            }
        }
        __syncthreads();
    }
}

// ---- merge split-K partials: Ab = (sum_s O_s) / (sum_s l_s), bf16
__global__ __launch_bounds__(256) void merge_kernel(
        const float* __restrict__ Opart, const float* __restrict__ Lpart,
        unsigned short* __restrict__ Ab) {
    int idx4 = (blockIdx.x * 256 + threadIdx.x) * 4;
    int row = idx4 >> 9;
    int h = (idx4 & 511) >> 6;
    float l = 0.f;
    float acc[4] = {0.f, 0.f, 0.f, 0.f};
    #pragma unroll
    for (int s = 0; s < SPLIT; ++s) {
        l += Lpart[((size_t)s * ROWS + row) * 8 + h];
        float4 u = *(const float4*)&Opart[(size_t)s * ROWS * EMB + idx4];
        acc[0] += u.x; acc[1] += u.y; acc[2] += u.z; acc[3] += u.w;
    }
    float inv = 1.f / l;
    ushort4 out = { f_to_bf16(acc[0] * inv), f_to_bf16(acc[1] * inv),
                    f_to_bf16(acc[2] * inv), f_to_bf16(acc[3] * inv) };
    *(ushort4*)&Ab[idx4] = out;
}

// ---- y = x + P; LayerNorm -> out. 4 rows per block (1 wave each).
__global__ __launch_bounds__(256) void ln_kernel(
        const float* __restrict__ xf, const unsigned short* __restrict__ xraw,
        const unsigned short* __restrict__ P,
        const float* __restrict__ gamma, const float* __restrict__ beta,
        void* __restrict__ out, const int* __restrict__ flag) {
    int row = blockIdx.x * 4 + (threadIdx.x >> 6);
    int t = threadIdx.x & 63;
    int fp32 = *flag;
    float v[8];
    float s = 0.f, ss = 0.f;
    const unsigned short* pp = &P[(size_t)row * EMB + t * 8];
    ushort4 p0 = *(const ushort4*)&pp[0];
    ushort4 p1 = *(const ushort4*)&pp[4];
    float pv[8] = { bf16_to_f(p0.x), bf16_to_f(p0.y), bf16_to_f(p0.z), bf16_to_f(p0.w),
                    bf16_to_f(p1.x), bf16_to_f(p1.y), bf16_to_f(p1.z), bf16_to_f(p1.w) };
    if (fp32) {
        const float* xp = &xf[(size_t)row * EMB + t * 8];
        for (int i = 0; i < 8; i += 4) {
            float4 x4 = *(const float4*)&xp[i];
            v[i] = x4.x + pv[i]; v[i+1] = x4.y + pv[i+1];
            v[i+2] = x4.z + pv[i+2]; v[i+3] = x4.w + pv[i+3];
        }
    } else {
        const unsigned short* xp = &xraw[(size_t)row * EMB + t * 8];
        ushort4 x0 = *(const ushort4*)&xp[0];
        ushort4 x1 = *(const ushort4*)&xp[4];
        v[0] = bf16_to_f(x0.x) + pv[0]; v[1] = bf16_to_f(x0.y) + pv[1];
        v[2] = bf16_to_f(x0.z) + pv[2]; v[3] = bf16_to_f(x0.w) + pv[3];
        v[4] = bf16_to_f(x1.x) + pv[4]; v[5] = bf16_to_f(x1.y) + pv[5];
        v[6] = bf16_to_f(x1.z) + pv[6]; v[7] = bf16_to_f(x1.w) + pv[7];
    }
    for (int i = 0; i < 8; ++i) { s += v[i]; ss += v[i] * v[i]; }
    for (int off = 32; off > 0; off >>= 1) {
        s  += __shfl_xor(s, off, 64);
        ss += __shfl_xor(ss, off, 64);
    }
    float mu = s * (1.f / 512.f);
    float var = ss * (1.f / 512.f) - mu * mu;
    float rs = rsqrtf(var + 1e-5f);
    for (int i = 0; i < 8; ++i) {
        int col = t * 8 + i;
        float y = (v[i] - mu) * rs * gamma[col] + beta[col];
        if (fp32) ((float*)out)[(size_t)row * EMB + col] = y;
        else      ((__hip_bfloat16*)out)[(size_t)row * EMB + col] = __float2bfloat16(y);
    }
}

extern "C" void kernel_launch(void* const* d_in, const int* in_sizes, int n_in,
                              void* d_out, int out_size, void* d_ws, size_t ws_size,
                              hipStream_t stream) {
    char* ws = (char*)d_ws;
    int* flag = (int*)ws;
    char* p = ws + 256;
    float* x_f  = (float*)p;           p += (size_t)ROWS * EMB * 4;          // 16MB
    float* bias_all = (float*)p;       p += 6 * 512 * 4;
    unsigned short* Wt   = (unsigned short*)p; p += (size_t)2048 * 512 * 2;  // 2MB
    unsigned short* QKVb = (unsigned short*)p; p += (size_t)ROWS * 1536 * 2; // 24MB
    unsigned short* Vt   = (unsigned short*)p; p += (size_t)16 * HD * SEQ * 2; // 8MB
    // shared region A: xb (conv_x -> QKV gemm) then Ab (merge -> O-proj)
    unsigned short* xb = (unsigned short*)p;
    unsigned short* Ab = (unsigned short*)p;   p += (size_t)ROWS * EMB * 2;  // 8MB
    // shared region B: Opart fp32 (attn -> merge) then Pb (O-proj -> ln)
    float* Opart = (float*)p;
    unsigned short* Pb = (unsigned short*)p;   p += (size_t)SPLIT * ROWS * EMB * 4; // 32MB
    float* Lpart = (float*)p;          p += (size_t)SPLIT * ROWS * 8 * 4;    // 0.5MB

    detect_kernel<<<1, 64, 0, stream>>>(d_in[0], flag);

    conv_x_kernel<<<ROWS * EMB / 1024, 256, 0, stream>>>(d_in[0], x_f, xb, flag);
    conv_wt_kernel<<<dim3(8, 8, 4), 256, 0, stream>>>(d_in[1], d_in[3], d_in[5], d_in[7], Wt, flag);
    conv_small_kernel<<<12, 256, 0, stream>>>(d_in[2], d_in[4], d_in[6], d_in[8], d_in[9], d_in[10],
                                              bias_all, flag);

    // fused QKV: N=1536; Q cols pre-scaled by QSCALE; V cols written transposed to Vt
    gemm_mfma_kernel<unsigned short><<<dim3(12, 64), 256, 0, stream>>>(
        xb, (const unsigned short*)d_in[0], flag, Wt, bias_all, QKVb, 1536, 512, Vt);

    attn_kernel<<<dim3(64 * HEADS * 2 * SPLIT), 256, 0, stream>>>(QKVb, Vt, Opart, Lpart);

    merge_kernel<<<ROWS * EMB / 1024, 256, 0, stream>>>(Opart, Lpart, Ab);

    // O-proj -> bf16
    gemm_mfma_kernel<unsigned short><<<dim3(4, 64), 256, 0, stream>>>(
        Ab, Ab, flag, Wt + (size_t)1536 * 512, bias_all + 1536, Pb, 512, 0,
        (unsigned short*)nullptr);

    ln_kernel<<<ROWS / 4, 256, 0, stream>>>(x_f, (const unsigned short*)d_in[0], Pb,
                                            bias_all + 4 * 512, bias_all + 5 * 512, d_out, flag);
}

// Round 2
// 254.971 us; speedup vs baseline: 1.4536x; 1.4536x over previous
//
#include <hip/hip_runtime.h>
#include <hip/hip_bf16.h>

// SelfAttention B=2,N=4096,E=512,H=8,D=64 — Round 12:
// R11 post-mortem: __launch_bounds__(256,5) forced VGPR 64->48 -> accumulator
// spill to scratch (FETCH 13.5->159MB, WRITE 37->183MB). Occupancy DID reach
// 5 blocks/CU (43%) via the 32768B LDS. R12 = R11 with launch_bounds back to
// (256,4): allocator free to use 64 VGPR; 5 blocks/CU still achievable at
// runtime (VGPR=64 allows 8 waves/SIMD; LDS=32768 allows 5 blocks/CU).

#define ROWS 8192
#define EMB  512
#define SEQ  4096
#define HEADS 8
#define HD   64
#define SPLIT 2
#define QSCALE 0.18033688011112042f   // 0.125 * log2(e)

typedef __attribute__((ext_vector_type(8))) short bf16x8;
typedef __attribute__((ext_vector_type(4))) short bf16x4;
typedef __attribute__((ext_vector_type(4))) float f32x4;

#define MFMA_K16(A, B, C) __builtin_amdgcn_mfma_f32_16x16x16bf16_1k(A, B, C, 0, 0, 0)

__device__ __forceinline__ float bf16_to_f(unsigned short u) {
    union { unsigned int i; float f; } v; v.i = ((unsigned int)u) << 16; return v.f;
}
__device__ __forceinline__ unsigned short f_to_bf16(float f) {
    union { __hip_bfloat16 h; unsigned short u; } v; v.h = __float2bfloat16(f); return v.u;
}
__device__ __forceinline__ unsigned int pack_bf16_trunc(float a, float b) {
    return (__float_as_uint(a) >> 16) | (__float_as_uint(b) & 0xFFFF0000u);
}
__device__ __forceinline__ void load_lds16(const void* g, void* l) {
    __builtin_amdgcn_global_load_lds(
        (const __attribute__((address_space(1))) void*)g,
        (__attribute__((address_space(3))) void*)l, 16, 0, 0);
}

// ---- dtype detection (fp32 buffers: random halfwords -> wild exponents)
__global__ void detect_kernel(const void* x, int* flag) {
    const unsigned short* p = (const unsigned short*)x;
    int t = threadIdx.x;
    int cnt = 0;
    for (int i = 0; i < 4; ++i) {
        unsigned short u = p[t * 4 + i];
        int e = (u >> 7) & 0xFF;
        if (e >= 140) cnt++;
    }
    for (int off = 32; off > 0; off >>= 1) cnt += __shfl_down(cnt, off, 64);
    if (t == 0) *flag = (cnt > 16) ? 1 : 0;   // 1 = fp32, 0 = bf16
}

// ---- only needed when input fp32: x -> x_f (fp32 copy) + xb (bf16)
__global__ __launch_bounds__(256) void conv_x_kernel(const void* __restrict__ x,
        float* __restrict__ xf, unsigned short* __restrict__ xb, const int* __restrict__ flag) {
    if (*flag == 0) return;
    int i = (blockIdx.x * 256 + threadIdx.x) * 4;
    float4 v = *(const float4*)((const float*)x + i);
    *(float4*)(xf + i) = v;
    ushort4 u = { f_to_bf16(v.x), f_to_bf16(v.y), f_to_bf16(v.z), f_to_bf16(v.w) };
    *(ushort4*)(xb + i) = u;
}

// ---- weights [K][N] -> Wt bf16 [mat*512 + n][k]
__global__ __launch_bounds__(256) void conv_wt_kernel(
        const void* W0, const void* W1, const void* W2, const void* W3,
        unsigned short* __restrict__ Wt, const int* __restrict__ flag) {
    __shared__ float T[64][65];
    int tid = threadIdx.x;
    int kt = blockIdx.x, nt = blockIdx.y, mat = blockIdx.z;
    const void* src = (mat == 0) ? W0 : (mat == 1) ? W1 : (mat == 2) ? W2 : W3;
    int fp32 = *flag;
    for (int ii = 0; ii < 4; ++ii) {
        int idx = tid + ii * 256;
        int i = idx >> 4, j = (idx & 15) * 4;
        size_t g = (size_t)(kt * 64 + i) * 512 + nt * 64 + j;
        if (fp32) {
            float4 v = *(const float4*)((const float*)src + g);
            T[i][j] = v.x; T[i][j+1] = v.y; T[i][j+2] = v.z; T[i][j+3] = v.w;
        } else {
            ushort4 u = *(const ushort4*)((const unsigned short*)src + g);
            T[i][j] = bf16_to_f(u.x); T[i][j+1] = bf16_to_f(u.y);
            T[i][j+2] = bf16_to_f(u.z); T[i][j+3] = bf16_to_f(u.w);
        }
    }
    __syncthreads();
    for (int ii = 0; ii < 2; ++ii) {
        int idx = tid + ii * 256;
        int j = idx >> 3, ch = idx & 7;
        unsigned short pk[8];
        for (int t = 0; t < 8; ++t) pk[t] = f_to_bf16(T[ch * 8 + t][j]);
        *(bf16x8*)&Wt[(size_t)(mat * 512 + nt * 64 + j) * 512 + kt * 64 + ch * 8] = *(bf16x8*)pk;
    }
}

// ---- 6 small vectors -> bias_all fp32 [6][512]: bq,bk,bv,bo,gamma,beta
__global__ __launch_bounds__(256) void conv_small_kernel(
        const void* b0, const void* b1, const void* b2, const void* b3,
        const void* b4, const void* b5, float* __restrict__ dst, const int* __restrict__ flag) {
    int idx = blockIdx.x * 256 + threadIdx.x;
    int mat = idx >> 9, off = idx & 511;
    const void* src = (mat == 0) ? b0 : (mat == 1) ? b1 : (mat == 2) ? b2 :
                      (mat == 3) ? b3 : (mat == 4) ? b4 : b5;
    float v;
    if (*flag) v = ((const float*)src)[off];
    else       v = bf16_to_f(((const unsigned short*)src)[off]);
    dst[idx] = v;
}

// ---- MFMA GEMM: C = A * Bt^T + bias, 128x128x64 tiles. A chosen per flag.
// If VtOut != null, cols >= 1024 (V block of fused QKV) are written TRANSPOSED
// to VtOut[bh][d][seq] (bf16) instead of to C.
// XCD-aware block swizzle (grid %8==0 in both uses): neutral-to-positive (R11),
// kept for A-panel L2 locality.
template <typename OutT>
__global__ __launch_bounds__(256) void gemm_mfma_kernel(
        const unsigned short* __restrict__ A_conv, const unsigned short* __restrict__ A_raw,
        const int* __restrict__ flag,
        const unsigned short* __restrict__ Bt,
        const float* __restrict__ bias, OutT* __restrict__ C, int ldc, int scale_cols,
        unsigned short* __restrict__ VtOut) {
    __shared__ unsigned short At[128 * 64];
    __shared__ unsigned short Bs[128 * 64];
    const unsigned short* A = (*flag) ? A_conv : A_raw;
    int tid = threadIdx.x;
    int wave = tid >> 6, lane = tid & 63;
    int l15 = lane & 15, quad = lane >> 4;

    int lin = blockIdx.x + gridDim.x * blockIdx.y;
    int nwg = gridDim.x * gridDim.y;
    int bx, by;
    if (nwg & 7) { bx = blockIdx.x; by = blockIdx.y; }
    else {
        int t = (lin & 7) * (nwg >> 3) + (lin >> 3);
        bx = t % gridDim.x; by = t / gridDim.x;
    }
    int m0 = by * 128, n0 = bx * 128;
    int wm = (wave & 1) * 64, wn = (wave >> 1) * 64;

    int rt = wave * 32 + (lane >> 3);
    int ch = (lane & 7) ^ ((lane >> 3) & 7);
    const unsigned short* ag = A  + (size_t)(m0 + rt) * 512 + ch * 8;
    const unsigned short* bg = Bt + (size_t)(n0 + rt) * 512 + ch * 8;

    f32x4 acc[4][4];
    for (int i = 0; i < 4; ++i) for (int j = 0; j < 4; ++j) acc[i][j] = (f32x4){0.f,0.f,0.f,0.f};

    for (int k0 = 0; k0 < 512; k0 += 64) {
        __syncthreads();
        #pragma unroll
        for (int j = 0; j < 4; ++j) {
            load_lds16(ag + (size_t)(j * 8) * 512 + k0, &At[(wave * 32 + j * 8) * 64]);
            load_lds16(bg + (size_t)(j * 8) * 512 + k0, &Bs[(wave * 32 + j * 8) * 64]);
        }
        __syncthreads();
        #pragma unroll
        for (int ks = 0; ks < 2; ++ks) {
            bf16x8 a[4], b[4];
            #pragma unroll
            for (int f = 0; f < 4; ++f) {
                int pc = ((ks * 4 + quad) ^ (l15 & 7)) * 8;
                a[f] = *(const bf16x8*)&At[(wm + f * 16 + l15) * 64 + pc];
                b[f] = *(const bf16x8*)&Bs[(wn + f * 16 + l15) * 64 + pc];
            }
            #pragma unroll
            for (int fm = 0; fm < 4; ++fm)
                #pragma unroll
                for (int fn = 0; fn < 4; ++fn)
                    acc[fm][fn] = __builtin_amdgcn_mfma_f32_16x16x32_bf16(a[fm], b[fn], acc[fm][fn], 0, 0, 0);
        }
    }
    #pragma unroll
    for (int fm = 0; fm < 4; ++fm) {
        #pragma unroll
        for (int fn = 0; fn < 4; ++fn) {
            int col = n0 + wn + fn * 16 + l15;
            float bia = bias[col];
            float sc = (col < scale_cols) ? QSCALE : 1.f;
            int rowbase = m0 + wm + fm * 16 + quad * 4;
            float v0 = (acc[fm][fn][0] + bia) * sc;
            float v1 = (acc[fm][fn][1] + bia) * sc;
            float v2 = (acc[fm][fn][2] + bia) * sc;
            float v3 = (acc[fm][fn][3] + bia) * sc;
            if (VtOut && col >= 1024) {
                int hd = col - 1024;
                int bh = (rowbase >> 12) * 8 + (hd >> 6);
                int d  = hd & 63;
                ushort4 pk = { f_to_bf16(v0), f_to_bf16(v1), f_to_bf16(v2), f_to_bf16(v3) };
                *(ushort4*)&VtOut[((size_t)(bh * 64 + d)) * SEQ + (rowbase & 4095)] = pk;
            } else {
                if constexpr (sizeof(OutT) == 2) {
                    C[(size_t)(rowbase + 0) * ldc + col] = (OutT)f_to_bf16(v0);
                    C[(size_t)(rowbase + 1) * ldc + col] = (OutT)f_to_bf16(v1);
                    C[(size_t)(rowbase + 2) * ldc + col] = (OutT)f_to_bf16(v2);
                    C[(size_t)(rowbase + 3) * ldc + col] = (OutT)f_to_bf16(v3);
                } else {
                    C[(size_t)(rowbase + 0) * ldc + col] = v0;
                    C[(size_t)(rowbase + 1) * ldc + col] = v1;
                    C[(size_t)(rowbase + 2) * ldc + col] = v2;
                    C[(size_t)(rowbase + 3) * ldc + col] = v3;
                }
            }
        }
    }
}

// ---- MFMA flash attention: LDS-staged K/V + register P. Block = 64 q, 4 waves in
// 2q x 2k split: wave = (qh = wave>>1)*32 q-rows x (kh = wave&1)*64 kcols of each
// 128-k tile. S^T = K·Q^T (swapped operands) -> exp2 -> bf16x4 A-frag -> K16 PV,
// no Ps LDS. Split-K=2, XCD swizzle. Epilogue: cross-kh O/l reduction via LDS.
// LDS = exactly 32768 (Lred aliased at +16384, past the 16KB Ored region)
// -> 5 blocks/CU at runtime. launch_bounds stays (256,4): (256,5) forced VGPR
// 64->48 and spilled the accumulators to scratch (R11: +290MB HBM traffic).
__global__ __launch_bounds__(256, 4) void attn_kernel(
        const unsigned short* __restrict__ QKV, const unsigned short* __restrict__ Vt,
        float* __restrict__ Opart, float* __restrict__ Lpart) {
    __shared__ __align__(16) unsigned char smem[32768];
    unsigned short* Ks = (unsigned short*)smem;              // [128 krow][64 d] swizzled
    unsigned short* Vs = (unsigned short*)(smem + 16384);    // [64 d][128 krow] swizzled
    float* Ored = (float*)smem;                              // epilogue [4 w][16 q][64 d] (16KB)
    float* Lred = (float*)(smem + 16384);                    // epilogue [4 w][2 t][16 q] (512B)

    int tid = threadIdx.x;
    int wave = tid >> 6, lane = tid & 63;
    int l15 = lane & 15, quad = lane >> 4;
    int qh = wave >> 1, kh = wave & 1;
    // grid 2048 = 8 xcd * 256 slots; grp = xcd + 8*(slot>>6); qt = slot&63
    int lin = blockIdx.x;
    int xcd = lin & 7, slot = lin >> 3;
    int grp = xcd + 8 * (slot >> 6);
    int qt = slot & 63;
    int h = grp & 7, b = (grp >> 3) & 1, s = grp >> 4;
    int bh = b * HEADS + h;
    int k0base = s * (SEQ / SPLIT);
    size_t qrow0 = (size_t)b * SEQ + qt * 64;

    // Q B-frags (n = q = l15, k = d): rows qh*32 + t*16 + l15. Pre-scaled by QSCALE.
    bf16x8 aq[2][2];
    #pragma unroll
    for (int t = 0; t < 2; ++t) {
        const unsigned short* qp = &QKV[(qrow0 + qh * 32 + t * 16 + l15) * 1536 + h * 64];
        aq[t][0] = *(const bf16x8*)&qp[quad * 8];
        aq[t][1] = *(const bf16x8*)&qp[32 + quad * 8];
    }
    f32x4 o[2][4];     // [t][db]: O[q = qh*32+t*16+quad*4+r][d = db*16+l15], partial over kh
    #pragma unroll
    for (int t = 0; t < 2; ++t)
        #pragma unroll
        for (int db = 0; db < 4; ++db) o[t][db] = (f32x4){0.f, 0.f, 0.f, 0.f};
    float lp[2] = {0.f, 0.f};   // per-lane: q = l15, summed over this lane's kcols

    // staging pointers (identical pattern to R9)
    int krt = wave * 32 + (lane >> 3);
    int kch = (lane & 7) ^ ((lane >> 3) & 7);
    const unsigned short* kg =
        &QKV[((size_t)b * SEQ + k0base + krt) * 1536 + 512 + h * 64 + kch * 8];

    for (int kt = 0; kt < SEQ / SPLIT / 128; ++kt) {
        __syncthreads();
        #pragma unroll
        for (int j = 0; j < 4; ++j) {
            load_lds16(kg + (size_t)(kt * 128 + j * 8) * 1536, &Ks[(wave * 32 + j * 8) * 64]);
            int d = wave * 16 + j * 4 + quad;
            int vch = l15 ^ (d & 7);
            load_lds16(&Vt[((size_t)bh * 64 + d) * SEQ + k0base + kt * 128 + vch * 8],
                       &Vs[(wave * 16 + j * 4) * 128]);
        }
        __syncthreads();

        #pragma unroll
        for (int nb = 0; nb < 4; ++nb) {
            int kc = kh * 64 + nb * 16;              // wave's kcol tile base in 128-tile
            // K A-frag (m = kcol = l15 within tile, k = d): rows kc + l15
            int krow = kc + l15;
            int key = krow & 7;
            bf16x8 kA0 = *(const bf16x8*)&Ks[krow * 64 + (quad ^ key) * 8];
            bf16x8 kA1 = *(const bf16x8*)&Ks[krow * 64 + ((4 + quad) ^ key) * 8];
            // V B-frags (k = kcol = quad*4+j, n = d = db*16+l15): 8B reads
            bf16x4 bv[4];
            #pragma unroll
            for (int db = 0; db < 4; ++db) {
                int d = db * 16 + l15;
                int c16 = (kc >> 3) + (quad >> 1);   // 16B chunk index
                int sub = (quad & 1) * 4;
                bv[db] = *(const bf16x4*)&Vs[d * 128 + ((c16 ^ (d & 7)) * 8) + sub];
            }
            #pragma unroll
            for (int t = 0; t < 2; ++t) {
                f32x4 sv = {0.f, 0.f, 0.f, 0.f};
                sv = __builtin_amdgcn_mfma_f32_16x16x32_bf16(kA0, aq[t][0], sv, 0, 0, 0);
                sv = __builtin_amdgcn_mfma_f32_16x16x32_bf16(kA1, aq[t][1], sv, 0, 0, 0);
                float p0 = __builtin_amdgcn_exp2f(sv[0]);
                float p1 = __builtin_amdgcn_exp2f(sv[1]);
                float p2 = __builtin_amdgcn_exp2f(sv[2]);
                float p3 = __builtin_amdgcn_exp2f(sv[3]);
                lp[t] += (p0 + p1) + (p2 + p3);
                union { unsigned int u[2]; bf16x4 v; } ap;
                ap.u[0] = pack_bf16_trunc(p0, p1);
                ap.u[1] = pack_bf16_trunc(p2, p3);
                #pragma unroll
                for (int db = 0; db < 4; ++db)
                    o[t][db] = MFMA_K16(ap.v, bv[db], o[t][db]);
            }
        }
    }

    // ---- epilogue: l over quads (shfl); O/l over kh pairs via LDS (aliases Ks/Vs)
    // Lred aliases Vs now -> barrier before storing (all waves must be done reading Vs).
    __syncthreads();
    #pragma unroll
    for (int t = 0; t < 2; ++t) {
        float v = lp[t];
        v += __shfl_xor(v, 16, 64);
        v += __shfl_xor(v, 32, 64);
        if (quad == 0) Lred[(wave * 2 + t) * 16 + l15] = v;
    }
    __syncthreads();
    float* myO = Ored + wave * (16 * 64);
    #pragma unroll
    for (int t = 0; t < 2; ++t) {
        #pragma unroll
        for (int db = 0; db < 4; ++db)
            #pragma unroll
            for (int r = 0; r < 4; ++r)
                myO[(quad * 4 + r) * 64 + db * 16 + l15] = o[t][db][r];
        __syncthreads();
        {
            int q_l = tid >> 3;              // 0..31
            int dg = tid & 7;
            int qh2 = q_l >> 4, qq = q_l & 15;
            const float* r0 = Ored + (qh2 * 2 + 0) * (16 * 64) + qq * 64 + dg * 8;
            const float* r1 = Ored + (qh2 * 2 + 1) * (16 * 64) + qq * 64 + dg * 8;
            float4 a0 = *(const float4*)&r0[0];
            float4 a1 = *(const float4*)&r0[4];
            float4 c0 = *(const float4*)&r1[0];
            float4 c1 = *(const float4*)&r1[4];
            float4 o0 = { a0.x + c0.x, a0.y + c0.y, a0.z + c0.z, a0.w + c0.w };
            float4 o1 = { a1.x + c1.x, a1.y + c1.y, a1.z + c1.z, a1.w + c1.w };
            size_t row = qrow0 + qh2 * 32 + t * 16 + qq;
            float* dst = &Opart[((size_t)s * ROWS + row) * EMB + h * 64 + dg * 8];
            *(float4*)&dst[0] = o0;
            *(float4*)&dst[4] = o1;
            if (dg == 0) {
                float lt = Lred[((qh2 * 2 + 0) * 2 + t) * 16 + qq] +
                           Lred[((qh2 * 2 + 1) * 2 + t) * 16 + qq];
                Lpart[((size_t)s * ROWS + row) * 8 + h] = lt;
            }
        }
        __syncthreads();
    }
}

// ---- merge split-K partials: Ab = (sum_s O_s) / (sum_s l_s), bf16
__global__ __launch_bounds__(256) void merge_kernel(
        const float* __restrict__ Opart, const float* __restrict__ Lpart,
        unsigned short* __restrict__ Ab) {
    int idx4 = (blockIdx.x * 256 + threadIdx.x) * 4;
    int row = idx4 >> 9;
    int h = (idx4 & 511) >> 6;
    float l = 0.f;
    float acc[4] = {0.f, 0.f, 0.f, 0.f};
    #pragma unroll
    for (int s = 0; s < SPLIT; ++s) {
        l += Lpart[((size_t)s * ROWS + row) * 8 + h];
        float4 u = *(const float4*)&Opart[(size_t)s * ROWS * EMB + idx4];
        acc[0] += u.x; acc[1] += u.y; acc[2] += u.z; acc[3] += u.w;
    }
    float inv = 1.f / l;
    ushort4 out = { f_to_bf16(acc[0] * inv), f_to_bf16(acc[1] * inv),
                    f_to_bf16(acc[2] * inv), f_to_bf16(acc[3] * inv) };
    *(ushort4*)&Ab[idx4] = out;
}

// ---- y = x + P; LayerNorm -> out. 4 rows per block (1 wave each).
__global__ __launch_bounds__(256) void ln_kernel(
        const float* __restrict__ xf, const unsigned short* __restrict__ xraw,
        const unsigned short* __restrict__ P,
        const float* __restrict__ gamma, const float* __restrict__ beta,
        void* __restrict__ out, const int* __restrict__ flag) {
    int row = blockIdx.x * 4 + (threadIdx.x >> 6);
    int t = threadIdx.x & 63;
    int fp32 = *flag;
    float v[8];
    float s = 0.f, ss = 0.f;
    const unsigned short* pp = &P[(size_t)row * EMB + t * 8];
    ushort4 p0 = *(const ushort4*)&pp[0];
    ushort4 p1 = *(const ushort4*)&pp[4];
    float pv[8] = { bf16_to_f(p0.x), bf16_to_f(p0.y), bf16_to_f(p0.z), bf16_to_f(p0.w),
                    bf16_to_f(p1.x), bf16_to_f(p1.y), bf16_to_f(p1.z), bf16_to_f(p1.w) };
    if (fp32) {
        const float* xp = &xf[(size_t)row * EMB + t * 8];
        for (int i = 0; i < 8; i += 4) {
            float4 x4 = *(const float4*)&xp[i];
            v[i] = x4.x + pv[i]; v[i+1] = x4.y + pv[i+1];
            v[i+2] = x4.z + pv[i+2]; v[i+3] = x4.w + pv[i+3];
        }
    } else {
        const unsigned short* xp = &xraw[(size_t)row * EMB + t * 8];
        ushort4 x0 = *(const ushort4*)&xp[0];
        ushort4 x1 = *(const ushort4*)&xp[4];
        v[0] = bf16_to_f(x0.x) + pv[0]; v[1] = bf16_to_f(x0.y) + pv[1];
        v[2] = bf16_to_f(x0.z) + pv[2]; v[3] = bf16_to_f(x0.w) + pv[3];
        v[4] = bf16_to_f(x1.x) + pv[4]; v[5] = bf16_to_f(x1.y) + pv[5];
        v[6] = bf16_to_f(x1.z) + pv[6]; v[7] = bf16_to_f(x1.w) + pv[7];
    }
    for (int i = 0; i < 8; ++i) { s += v[i]; ss += v[i] * v[i]; }
    for (int off = 32; off > 0; off >>= 1) {
        s  += __shfl_xor(s, off, 64);
        ss += __shfl_xor(ss, off, 64);
    }
    float mu = s * (1.f / 512.f);
    float var = ss * (1.f / 512.f) - mu * mu;
    float rs = rsqrtf(var + 1e-5f);
    for (int i = 0; i < 8; ++i) {
        int col = t * 8 + i;
        float y = (v[i] - mu) * rs * gamma[col] + beta[col];
        if (fp32) ((float*)out)[(size_t)row * EMB + col] = y;
        else      ((__hip_bfloat16*)out)[(size_t)row * EMB + col] = __float2bfloat16(y);
    }
}

extern "C" void kernel_launch(void* const* d_in, const int* in_sizes, int n_in,
                              void* d_out, int out_size, void* d_ws, size_t ws_size,
                              hipStream_t stream) {
    char* ws = (char*)d_ws;
    int* flag = (int*)ws;
    char* p = ws + 256;
    float* x_f  = (float*)p;           p += (size_t)ROWS * EMB * 4;          // 16MB
    float* bias_all = (float*)p;       p += 6 * 512 * 4;
    unsigned short* Wt   = (unsigned short*)p; p += (size_t)2048 * 512 * 2;  // 2MB
    unsigned short* QKVb = (unsigned short*)p; p += (size_t)ROWS * 1536 * 2; // 24MB
    unsigned short* Vt   = (unsigned short*)p; p += (size_t)16 * HD * SEQ * 2; // 8MB
    // shared region A: xb (conv_x -> QKV gemm) then Ab (merge -> O-proj)
    unsigned short* xb = (unsigned short*)p;
    unsigned short* Ab = (unsigned short*)p;   p += (size_t)ROWS * EMB * 2;  // 8MB
    // shared region B: Opart fp32 (attn -> merge) then Pb (O-proj -> ln)
    float* Opart = (float*)p;
    unsigned short* Pb = (unsigned short*)p;   p += (size_t)SPLIT * ROWS * EMB * 4; // 32MB
    float* Lpart = (float*)p;          p += (size_t)SPLIT * ROWS * 8 * 4;    // 0.5MB

    detect_kernel<<<1, 64, 0, stream>>>(d_in[0], flag);

    conv_x_kernel<<<ROWS * EMB / 1024, 256, 0, stream>>>(d_in[0], x_f, xb, flag);
    conv_wt_kernel<<<dim3(8, 8, 4), 256, 0, stream>>>(d_in[1], d_in[3], d_in[5], d_in[7], Wt, flag);
    conv_small_kernel<<<12, 256, 0, stream>>>(d_in[2], d_in[4], d_in[6], d_in[8], d_in[9], d_in[10],
                                              bias_all, flag);

    // fused QKV: N=1536; Q cols pre-scaled by QSCALE; V cols written transposed to Vt
    gemm_mfma_kernel<unsigned short><<<dim3(12, 64), 256, 0, stream>>>(
        xb, (const unsigned short*)d_in[0], flag, Wt, bias_all, QKVb, 1536, 512, Vt);

    attn_kernel<<<dim3(64 * HEADS * 2 * SPLIT), 256, 0, stream>>>(QKVb, Vt, Opart, Lpart);

    merge_kernel<<<ROWS * EMB / 1024, 256, 0, stream>>>(Opart, Lpart, Ab);

    // O-proj -> bf16
    gemm_mfma_kernel<unsigned short><<<dim3(4, 64), 256, 0, stream>>>(
        Ab, Ab, flag, Wt + (size_t)1536 * 512, bias_all + 1536, Pb, 512, 0,
        (unsigned short*)nullptr);

    ln_kernel<<<ROWS / 4, 256, 0, stream>>>(x_f, (const unsigned short*)d_in[0], Pb,
                                            bias_all + 4 * 512, bias_all + 5 * 512, d_out, flag);
}

// Round 3
// 245.472 us; speedup vs baseline: 1.5098x; 1.0387x over previous
//
#include <hip/hip_runtime.h>
#include <hip/hip_bf16.h>

// SelfAttention B=2,N=4096,E=512,H=8,D=64 — Round 13:
// R12 post-mortem: occupancy (34->43%) never moved perf; loop is latency-bound
// (all pipes 43-46%, single-buffer stage->drain->compute exposes full staging
// latency). R13:
//  (a) attn: 2-phase double-buffered pipeline (T3 minimum recipe), KVBLK 128->64
//      so 2x(K+V) still = 32KB LDS. One barrier/iter: vmcnt(0); s_barrier;
//      STAGE(next); compute(cur) — next tile's gload_lds in flight during compute.
//  (b) SPLIT=1: merge_kernel removed; attn normalizes (1/l) in epilogue and
//      writes bf16 Ab directly (no fp32 Opart round-trip). x_f copy removed;
//      ln reads d_in[0] directly in the fp32 case.

#define ROWS 8192
#define EMB  512
#define SEQ  4096
#define HEADS 8
#define HD   64
#define QSCALE 0.18033688011112042f   // 0.125 * log2(e)

typedef __attribute__((ext_vector_type(8))) short bf16x8;
typedef __attribute__((ext_vector_type(4))) short bf16x4;
typedef __attribute__((ext_vector_type(4))) float f32x4;

#define MFMA_K16(A, B, C) __builtin_amdgcn_mfma_f32_16x16x16bf16_1k(A, B, C, 0, 0, 0)

__device__ __forceinline__ float bf16_to_f(unsigned short u) {
    union { unsigned int i; float f; } v; v.i = ((unsigned int)u) << 16; return v.f;
}
__device__ __forceinline__ unsigned short f_to_bf16(float f) {
    union { __hip_bfloat16 h; unsigned short u; } v; v.h = __float2bfloat16(f); return v.u;
}
__device__ __forceinline__ unsigned int pack_bf16_trunc(float a, float b) {
    return (__float_as_uint(a) >> 16) | (__float_as_uint(b) & 0xFFFF0000u);
}
__device__ __forceinline__ void load_lds16(const void* g, void* l) {
    __builtin_amdgcn_global_load_lds(
        (const __attribute__((address_space(1))) void*)g,
        (__attribute__((address_space(3))) void*)l, 16, 0, 0);
}

// ---- dtype detection (fp32 buffers: random halfwords -> wild exponents)
__global__ void detect_kernel(const void* x, int* flag) {
    const unsigned short* p = (const unsigned short*)x;
    int t = threadIdx.x;
    int cnt = 0;
    for (int i = 0; i < 4; ++i) {
        unsigned short u = p[t * 4 + i];
        int e = (u >> 7) & 0xFF;
        if (e >= 140) cnt++;
    }
    for (int off = 32; off > 0; off >>= 1) cnt += __shfl_down(cnt, off, 64);
    if (t == 0) *flag = (cnt > 16) ? 1 : 0;   // 1 = fp32, 0 = bf16
}

// ---- only needed when input fp32: x -> xb (bf16)
__global__ __launch_bounds__(256) void conv_x_kernel(const void* __restrict__ x,
        unsigned short* __restrict__ xb, const int* __restrict__ flag) {
    if (*flag == 0) return;
    int i = (blockIdx.x * 256 + threadIdx.x) * 4;
    float4 v = *(const float4*)((const float*)x + i);
    ushort4 u = { f_to_bf16(v.x), f_to_bf16(v.y), f_to_bf16(v.z), f_to_bf16(v.w) };
    *(ushort4*)(xb + i) = u;
}

// ---- weights [K][N] -> Wt bf16 [mat*512 + n][k]
__global__ __launch_bounds__(256) void conv_wt_kernel(
        const void* W0, const void* W1, const void* W2, const void* W3,
        unsigned short* __restrict__ Wt, const int* __restrict__ flag) {
    __shared__ float T[64][65];
    int tid = threadIdx.x;
    int kt = blockIdx.x, nt = blockIdx.y, mat = blockIdx.z;
    const void* src = (mat == 0) ? W0 : (mat == 1) ? W1 : (mat == 2) ? W2 : W3;
    int fp32 = *flag;
    for (int ii = 0; ii < 4; ++ii) {
        int idx = tid + ii * 256;
        int i = idx >> 4, j = (idx & 15) * 4;
        size_t g = (size_t)(kt * 64 + i) * 512 + nt * 64 + j;
        if (fp32) {
            float4 v = *(const float4*)((const float*)src + g);
            T[i][j] = v.x; T[i][j+1] = v.y; T[i][j+2] = v.z; T[i][j+3] = v.w;
        } else {
            ushort4 u = *(const ushort4*)((const unsigned short*)src + g);
            T[i][j] = bf16_to_f(u.x); T[i][j+1] = bf16_to_f(u.y);
            T[i][j+2] = bf16_to_f(u.z); T[i][j+3] = bf16_to_f(u.w);
        }
    }
    __syncthreads();
    for (int ii = 0; ii < 2; ++ii) {
        int idx = tid + ii * 256;
        int j = idx >> 3, ch = idx & 7;
        unsigned short pk[8];
        for (int t = 0; t < 8; ++t) pk[t] = f_to_bf16(T[ch * 8 + t][j]);
        *(bf16x8*)&Wt[(size_t)(mat * 512 + nt * 64 + j) * 512 + kt * 64 + ch * 8] = *(bf16x8*)pk;
    }
}

// ---- 6 small vectors -> bias_all fp32 [6][512]: bq,bk,bv,bo,gamma,beta
__global__ __launch_bounds__(256) void conv_small_kernel(
        const void* b0, const void* b1, const void* b2, const void* b3,
        const void* b4, const void* b5, float* __restrict__ dst, const int* __restrict__ flag) {
    int idx = blockIdx.x * 256 + threadIdx.x;
    int mat = idx >> 9, off = idx & 511;
    const void* src = (mat == 0) ? b0 : (mat == 1) ? b1 : (mat == 2) ? b2 :
                      (mat == 3) ? b3 : (mat == 4) ? b4 : b5;
    float v;
    if (*flag) v = ((const float*)src)[off];
    else       v = bf16_to_f(((const unsigned short*)src)[off]);
    dst[idx] = v;
}

// ---- MFMA GEMM: C = A * Bt^T + bias, 128x128x64 tiles. A chosen per flag.
// If VtOut != null, cols >= 1024 (V block of fused QKV) are written TRANSPOSED
// to VtOut[bh][d][seq] (bf16) instead of to C.
// XCD-aware block swizzle (grid %8==0 in both uses).
template <typename OutT>
__global__ __launch_bounds__(256) void gemm_mfma_kernel(
        const unsigned short* __restrict__ A_conv, const unsigned short* __restrict__ A_raw,
        const int* __restrict__ flag,
        const unsigned short* __restrict__ Bt,
        const float* __restrict__ bias, OutT* __restrict__ C, int ldc, int scale_cols,
        unsigned short* __restrict__ VtOut) {
    __shared__ unsigned short At[128 * 64];
    __shared__ unsigned short Bs[128 * 64];
    const unsigned short* A = (*flag) ? A_conv : A_raw;
    int tid = threadIdx.x;
    int wave = tid >> 6, lane = tid & 63;
    int l15 = lane & 15, quad = lane >> 4;

    int lin = blockIdx.x + gridDim.x * blockIdx.y;
    int nwg = gridDim.x * gridDim.y;
    int bx, by;
    if (nwg & 7) { bx = blockIdx.x; by = blockIdx.y; }
    else {
        int t = (lin & 7) * (nwg >> 3) + (lin >> 3);
        bx = t % gridDim.x; by = t / gridDim.x;
    }
    int m0 = by * 128, n0 = bx * 128;
    int wm = (wave & 1) * 64, wn = (wave >> 1) * 64;

    int rt = wave * 32 + (lane >> 3);
    int ch = (lane & 7) ^ ((lane >> 3) & 7);
    const unsigned short* ag = A  + (size_t)(m0 + rt) * 512 + ch * 8;
    const unsigned short* bg = Bt + (size_t)(n0 + rt) * 512 + ch * 8;

    f32x4 acc[4][4];
    for (int i = 0; i < 4; ++i) for (int j = 0; j < 4; ++j) acc[i][j] = (f32x4){0.f,0.f,0.f,0.f};

    for (int k0 = 0; k0 < 512; k0 += 64) {
        __syncthreads();
        #pragma unroll
        for (int j = 0; j < 4; ++j) {
            load_lds16(ag + (size_t)(j * 8) * 512 + k0, &At[(wave * 32 + j * 8) * 64]);
            load_lds16(bg + (size_t)(j * 8) * 512 + k0, &Bs[(wave * 32 + j * 8) * 64]);
        }
        __syncthreads();
        #pragma unroll
        for (int ks = 0; ks < 2; ++ks) {
            bf16x8 a[4], b[4];
            #pragma unroll
            for (int f = 0; f < 4; ++f) {
                int pc = ((ks * 4 + quad) ^ (l15 & 7)) * 8;
                a[f] = *(const bf16x8*)&At[(wm + f * 16 + l15) * 64 + pc];
                b[f] = *(const bf16x8*)&Bs[(wn + f * 16 + l15) * 64 + pc];
            }
            #pragma unroll
            for (int fm = 0; fm < 4; ++fm)
                #pragma unroll
                for (int fn = 0; fn < 4; ++fn)
                    acc[fm][fn] = __builtin_amdgcn_mfma_f32_16x16x32_bf16(a[fm], b[fn], acc[fm][fn], 0, 0, 0);
        }
    }
    #pragma unroll
    for (int fm = 0; fm < 4; ++fm) {
        #pragma unroll
        for (int fn = 0; fn < 4; ++fn) {
            int col = n0 + wn + fn * 16 + l15;
            float bia = bias[col];
            float sc = (col < scale_cols) ? QSCALE : 1.f;
            int rowbase = m0 + wm + fm * 16 + quad * 4;
            float v0 = (acc[fm][fn][0] + bia) * sc;
            float v1 = (acc[fm][fn][1] + bia) * sc;
            float v2 = (acc[fm][fn][2] + bia) * sc;
            float v3 = (acc[fm][fn][3] + bia) * sc;
            if (VtOut && col >= 1024) {
                int hd = col - 1024;
                int bh = (rowbase >> 12) * 8 + (hd >> 6);
                int d  = hd & 63;
                ushort4 pk = { f_to_bf16(v0), f_to_bf16(v1), f_to_bf16(v2), f_to_bf16(v3) };
                *(ushort4*)&VtOut[((size_t)(bh * 64 + d)) * SEQ + (rowbase & 4095)] = pk;
            } else {
                if constexpr (sizeof(OutT) == 2) {
                    C[(size_t)(rowbase + 0) * ldc + col] = (OutT)f_to_bf16(v0);
                    C[(size_t)(rowbase + 1) * ldc + col] = (OutT)f_to_bf16(v1);
                    C[(size_t)(rowbase + 2) * ldc + col] = (OutT)f_to_bf16(v2);
                    C[(size_t)(rowbase + 3) * ldc + col] = (OutT)f_to_bf16(v3);
                } else {
                    C[(size_t)(rowbase + 0) * ldc + col] = v0;
                    C[(size_t)(rowbase + 1) * ldc + col] = v1;
                    C[(size_t)(rowbase + 2) * ldc + col] = v2;
                    C[(size_t)(rowbase + 3) * ldc + col] = v3;
                }
            }
        }
    }
}

// ---- MFMA flash attention, 2-phase double-buffered (T3 minimum recipe).
// Block = 64 q, 4 waves, 2q x 2k split. KVBLK = 64 kcols/tile so the double
// buffer fits 32KB: Ks[2] @ {0,8K}, Vs[2] @ {16K,24K}. Per iter: vmcnt(0) +
// s_barrier (buf[cur] ready, prev readers done), STAGE(buf[cur^1], kt+1)
// in flight during compute(buf[cur]). S^T = K·Q^T -> exp2 -> bf16x4 -> K16 PV.
// SPLIT=1: epilogue normalizes by 1/l and writes bf16 directly.
__global__ __launch_bounds__(256, 4) void attn_kernel(
        const unsigned short* __restrict__ QKV, const unsigned short* __restrict__ Vt,
        unsigned short* __restrict__ Ab) {
    __shared__ __align__(16) unsigned char smem[32768];
    float* Ored = (float*)smem;                 // epilogue [4 w][16 q][64 d] (16KB)
    float* Lred = (float*)(smem + 16384);       // epilogue [4 w][2 t][16 q] (512B)

    int tid = threadIdx.x;
    int wave = tid >> 6, lane = tid & 63;
    int l15 = lane & 15, quad = lane >> 4;
    int qh = wave >> 1, kh = wave & 1;
    // grid 1024 = 8 xcd * 128 slots; grp = xcd + 8*(slot>>6); qt = slot&63
    int lin = blockIdx.x;
    int xcd = lin & 7, slot = lin >> 3;
    int grp = xcd + 8 * (slot >> 6);      // 16 (b,h) groups, 2 per XCD
    int qt = slot & 63;
    int h = grp & 7, b = grp >> 3;
    int bh = b * HEADS + h;
    size_t qrow0 = (size_t)b * SEQ + qt * 64;

    // Q B-frags (n = q = l15, k = d): rows qh*32 + t*16 + l15. Pre-scaled by QSCALE.
    bf16x8 aq[2][2];
    #pragma unroll
    for (int t = 0; t < 2; ++t) {
        const unsigned short* qp = &QKV[(qrow0 + qh * 32 + t * 16 + l15) * 1536 + h * 64];
        aq[t][0] = *(const bf16x8*)&qp[quad * 8];
        aq[t][1] = *(const bf16x8*)&qp[32 + quad * 8];
    }
    f32x4 o[2][4];     // [t][db]: O[q = qh*32+t*16+quad*4+r][d = db*16+l15], partial over kh
    #pragma unroll
    for (int t = 0; t < 2; ++t)
        #pragma unroll
        for (int db = 0; db < 4; ++db) o[t][db] = (f32x4){0.f, 0.f, 0.f, 0.f};
    float lp[2] = {0.f, 0.f};   // per-lane: q = l15, summed over this lane's kcols

    // staging base pointers. Per gload_lds instr: 1KB = 8 rows x 128B.
    // lane: row offset = lane>>3, 16B chunk = lane&7, XOR-swizzled by row&7.
    int r8 = lane >> 3;
    int kch = (lane & 7) ^ (r8 & 7);
    const unsigned short* kg = &QKV[((size_t)b * SEQ + r8) * 1536 + 512 + h * 64 + kch * 8];
    const unsigned short* vg = &Vt[((size_t)bh * 64 + wave * 16 + r8) * SEQ + kch * 8];

#define STAGE(buf, kt2) do {                                                          \
        unsigned short* Ksb = (unsigned short*)(smem + (buf) * 8192);                 \
        unsigned short* Vsb = (unsigned short*)(smem + 16384 + (buf) * 8192);         \
        load_lds16(kg + (size_t)((kt2) * 64 + wave * 16) * 1536,                      \
                   &Ksb[(wave * 16) * 64]);                                           \
        load_lds16(kg + (size_t)((kt2) * 64 + wave * 16 + 8) * 1536,                  \
                   &Ksb[(wave * 16 + 8) * 64]);                                       \
        load_lds16(vg + (size_t)((kt2) * 64), &Vsb[(wave * 16) * 64]);                \
        load_lds16(vg + (size_t)((kt2) * 64) + (size_t)8 * SEQ,                       \
                   &Vsb[(wave * 16 + 8) * 64]);                                       \
    } while (0)

    STAGE(0, 0);   // prologue

    for (int kt = 0; kt < SEQ / 64; ++kt) {
        int cur = kt & 1;
        // wait for buf[cur]'s loads (issued last iter, in flight during its compute);
        // barrier also guarantees all waves finished reading buf[cur^1].
        asm volatile("s_waitcnt vmcnt(0)" ::: "memory");
        __builtin_amdgcn_sched_barrier(0);
        asm volatile("s_barrier" ::: "memory");
        __builtin_amdgcn_sched_barrier(0);
        if (kt + 1 < SEQ / 64) STAGE(cur ^ 1, kt + 1);   // overlaps with compute below

        const unsigned short* Ksc = (const unsigned short*)(smem + cur * 8192);
        const unsigned short* Vsc = (const unsigned short*)(smem + 16384 + cur * 8192);
        #pragma unroll
        for (int nb = 0; nb < 2; ++nb) {
            int kc = kh * 32 + nb * 16;              // wave's kcol tile base in 64-tile
            int krow = kc + l15;
            int key = krow & 7;
            bf16x8 kA0 = *(const bf16x8*)&Ksc[krow * 64 + (quad ^ key) * 8];
            bf16x8 kA1 = *(const bf16x8*)&Ksc[krow * 64 + ((4 + quad) ^ key) * 8];
            // V B-frags (k = kcol = quad*4+j, n = d = db*16+l15): 8B reads
            bf16x4 bv[4];
            #pragma unroll
            for (int db = 0; db < 4; ++db) {
                int d = db * 16 + l15;
                int c16 = (kc >> 3) + (quad >> 1);   // 16B chunk index (0..7)
                int sub = (quad & 1) * 4;
                bv[db] = *(const bf16x4*)&Vsc[d * 64 + ((c16 ^ (d & 7)) * 8) + sub];
            }
            #pragma unroll
            for (int t = 0; t < 2; ++t) {
                f32x4 sv = {0.f, 0.f, 0.f, 0.f};
                sv = __builtin_amdgcn_mfma_f32_16x16x32_bf16(kA0, aq[t][0], sv, 0, 0, 0);
                sv = __builtin_amdgcn_mfma_f32_16x16x32_bf16(kA1, aq[t][1], sv, 0, 0, 0);
                float p0 = __builtin_amdgcn_exp2f(sv[0]);
                float p1 = __builtin_amdgcn_exp2f(sv[1]);
                float p2 = __builtin_amdgcn_exp2f(sv[2]);
                float p3 = __builtin_amdgcn_exp2f(sv[3]);
                lp[t] += (p0 + p1) + (p2 + p3);
                union { unsigned int u[2]; bf16x4 v; } ap;
                ap.u[0] = pack_bf16_trunc(p0, p1);
                ap.u[1] = pack_bf16_trunc(p2, p3);
                #pragma unroll
                for (int db = 0; db < 4; ++db)
                    o[t][db] = MFMA_K16(ap.v, bv[db], o[t][db]);
            }
        }
        __builtin_amdgcn_sched_barrier(0);
    }
#undef STAGE

    // ---- epilogue: l over quads (shfl); O/l over kh pairs via LDS; write bf16.
    __syncthreads();
    #pragma unroll
    for (int t = 0; t < 2; ++t) {
        float v = lp[t];
        v += __shfl_xor(v, 16, 64);
        v += __shfl_xor(v, 32, 64);
        if (quad == 0) Lred[(wave * 2 + t) * 16 + l15] = v;
    }
    __syncthreads();
    float* myO = Ored + wave * (16 * 64);
    #pragma unroll
    for (int t = 0; t < 2; ++t) {
        #pragma unroll
        for (int db = 0; db < 4; ++db)
            #pragma unroll
            for (int r = 0; r < 4; ++r)
                myO[(quad * 4 + r) * 64 + db * 16 + l15] = o[t][db][r];
        __syncthreads();
        {
            int q_l = tid >> 3;              // 0..31
            int dg = tid & 7;
            int qh2 = q_l >> 4, qq = q_l & 15;
            const float* r0 = Ored + (qh2 * 2 + 0) * (16 * 64) + qq * 64 + dg * 8;
            const float* r1 = Ored + (qh2 * 2 + 1) * (16 * 64) + qq * 64 + dg * 8;
            float4 a0 = *(const float4*)&r0[0];
            float4 a1 = *(const float4*)&r0[4];
            float4 c0 = *(const float4*)&r1[0];
            float4 c1 = *(const float4*)&r1[4];
            float lt = Lred[((qh2 * 2 + 0) * 2 + t) * 16 + qq] +
                       Lred[((qh2 * 2 + 1) * 2 + t) * 16 + qq];
            float inv = 1.f / lt;
            size_t row = qrow0 + qh2 * 32 + t * 16 + qq;
            unsigned short* dst = &Ab[row * EMB + h * 64 + dg * 8];
            ushort4 lo = { f_to_bf16((a0.x + c0.x) * inv), f_to_bf16((a0.y + c0.y) * inv),
                           f_to_bf16((a0.z + c0.z) * inv), f_to_bf16((a0.w + c0.w) * inv) };
            ushort4 hi = { f_to_bf16((a1.x + c1.x) * inv), f_to_bf16((a1.y + c1.y) * inv),
                           f_to_bf16((a1.z + c1.z) * inv), f_to_bf16((a1.w + c1.w) * inv) };
            *(ushort4*)&dst[0] = lo;
            *(ushort4*)&dst[4] = hi;
        }
        __syncthreads();
    }
}

// ---- y = x + P; LayerNorm -> out. 4 rows per block (1 wave each).
__global__ __launch_bounds__(256) void ln_kernel(
        const float* __restrict__ xf, const unsigned short* __restrict__ xraw,
        const unsigned short* __restrict__ P,
        const float* __restrict__ gamma, const float* __restrict__ beta,
        void* __restrict__ out, const int* __restrict__ flag) {
    int row = blockIdx.x * 4 + (threadIdx.x >> 6);
    int t = threadIdx.x & 63;
    int fp32 = *flag;
    float v[8];
    float s = 0.f, ss = 0.f;
    const unsigned short* pp = &P[(size_t)row * EMB + t * 8];
    ushort4 p0 = *(const ushort4*)&pp[0];
    ushort4 p1 = *(const ushort4*)&pp[4];
    float pv[8] = { bf16_to_f(p0.x), bf16_to_f(p0.y), bf16_to_f(p0.z), bf16_to_f(p0.w),
                    bf16_to_f(p1.x), bf16_to_f(p1.y), bf16_to_f(p1.z), bf16_to_f(p1.w) };
    if (fp32) {
        const float* xp = &xf[(size_t)row * EMB + t * 8];
        for (int i = 0; i < 8; i += 4) {
            float4 x4 = *(const float4*)&xp[i];
            v[i] = x4.x + pv[i]; v[i+1] = x4.y + pv[i+1];
            v[i+2] = x4.z + pv[i+2]; v[i+3] = x4.w + pv[i+3];
        }
    } else {
        const unsigned short* xp = &xraw[(size_t)row * EMB + t * 8];
        ushort4 x0 = *(const ushort4*)&xp[0];
        ushort4 x1 = *(const ushort4*)&xp[4];
        v[0] = bf16_to_f(x0.x) + pv[0]; v[1] = bf16_to_f(x0.y) + pv[1];
        v[2] = bf16_to_f(x0.z) + pv[2]; v[3] = bf16_to_f(x0.w) + pv[3];
        v[4] = bf16_to_f(x1.x) + pv[4]; v[5] = bf16_to_f(x1.y) + pv[5];
        v[6] = bf16_to_f(x1.z) + pv[6]; v[7] = bf16_to_f(x1.w) + pv[7];
    }
    for (int i = 0; i < 8; ++i) { s += v[i]; ss += v[i] * v[i]; }
    for (int off = 32; off > 0; off >>= 1) {
        s  += __shfl_xor(s, off, 64);
        ss += __shfl_xor(ss, off, 64);
    }
    float mu = s * (1.f / 512.f);
    float var = ss * (1.f / 512.f) - mu * mu;
    float rs = rsqrtf(var + 1e-5f);
    for (int i = 0; i < 8; ++i) {
        int col = t * 8 + i;
        float y = (v[i] - mu) * rs * gamma[col] + beta[col];
        if (fp32) ((float*)out)[(size_t)row * EMB + col] = y;
        else      ((__hip_bfloat16*)out)[(size_t)row * EMB + col] = __float2bfloat16(y);
    }
}

extern "C" void kernel_launch(void* const* d_in, const int* in_sizes, int n_in,
                              void* d_out, int out_size, void* d_ws, size_t ws_size,
                              hipStream_t stream) {
    char* ws = (char*)d_ws;
    int* flag = (int*)ws;
    char* p = ws + 256;
    float* bias_all = (float*)p;       p += 6 * 512 * 4;
    unsigned short* Wt   = (unsigned short*)p; p += (size_t)2048 * 512 * 2;  // 2MB
    unsigned short* QKVb = (unsigned short*)p; p += (size_t)ROWS * 1536 * 2; // 24MB
    unsigned short* Vt   = (unsigned short*)p; p += (size_t)16 * HD * SEQ * 2; // 8MB
    // shared region: xb (conv_x -> QKV gemm) then Ab (attn -> O-proj)
    unsigned short* xb = (unsigned short*)p;
    unsigned short* Ab = (unsigned short*)p;   p += (size_t)ROWS * EMB * 2;  // 8MB
    unsigned short* Pb = (unsigned short*)p;   p += (size_t)ROWS * EMB * 2;  // 8MB

    detect_kernel<<<1, 64, 0, stream>>>(d_in[0], flag);

    conv_x_kernel<<<ROWS * EMB / 1024, 256, 0, stream>>>(d_in[0], xb, flag);
    conv_wt_kernel<<<dim3(8, 8, 4), 256, 0, stream>>>(d_in[1], d_in[3], d_in[5], d_in[7], Wt, flag);
    conv_small_kernel<<<12, 256, 0, stream>>>(d_in[2], d_in[4], d_in[6], d_in[8], d_in[9], d_in[10],
                                              bias_all, flag);

    // fused QKV: N=1536; Q cols pre-scaled by QSCALE; V cols written transposed to Vt
    gemm_mfma_kernel<unsigned short><<<dim3(12, 64), 256, 0, stream>>>(
        xb, (const unsigned short*)d_in[0], flag, Wt, bias_all, QKVb, 1536, 512, Vt);

    attn_kernel<<<dim3(1024), 256, 0, stream>>>(QKVb, Vt, Ab);

    // O-proj -> bf16
    gemm_mfma_kernel<unsigned short><<<dim3(4, 64), 256, 0, stream>>>(
        Ab, Ab, flag, Wt + (size_t)1536 * 512, bias_all + 1536, Pb, 512, 0,
        (unsigned short*)nullptr);

    ln_kernel<<<ROWS / 4, 256, 0, stream>>>((const float*)d_in[0],
                                            (const unsigned short*)d_in[0], Pb,
                                            bias_all + 4 * 512, bias_all + 5 * 512, d_out, flag);
}

// Round 4
// 237.961 us; speedup vs baseline: 1.5575x; 1.0316x over previous
//
#include <hip/hip_runtime.h>
#include <hip/hip_bf16.h>

// SelfAttention B=2,N=4096,E=512,H=8,D=64 — Round 14:
// R13 post-mortem: attn MfmaUtil+VALUBusy = 100% -> issue-bound at both pipes'
// arithmetic floor; only issue-cycle removal helps. Non-attn = 147us of 245 —
// GEMMs still run the single-buffered drain-stall loop.
// R14: (a) gemm: 2-phase double-buffered (R13-attn recipe), BK=64, LDS 64KB,
//          vmcnt(0)+barrier+STAGE(next)+compute(cur) per K-step.
//      (b) attn: pack_bf16 via single v_perm_b32; s_setprio(1) around MFMA
//          clusters (m191 attn lever).

#define ROWS 8192
#define EMB  512
#define SEQ  4096
#define HEADS 8
#define HD   64
#define QSCALE 0.18033688011112042f   // 0.125 * log2(e)

typedef __attribute__((ext_vector_type(8))) short bf16x8;
typedef __attribute__((ext_vector_type(4))) short bf16x4;
typedef __attribute__((ext_vector_type(4))) float f32x4;

#define MFMA_K16(A, B, C) __builtin_amdgcn_mfma_f32_16x16x16bf16_1k(A, B, C, 0, 0, 0)

__device__ __forceinline__ float bf16_to_f(unsigned short u) {
    union { unsigned int i; float f; } v; v.i = ((unsigned int)u) << 16; return v.f;
}
__device__ __forceinline__ unsigned short f_to_bf16(float f) {
    union { __hip_bfloat16 h; unsigned short u; } v; v.h = __float2bfloat16(f); return v.u;
}
// low16 = hi16(a), high16 = hi16(b) — single v_perm_b32
__device__ __forceinline__ unsigned int pack_bf16_trunc(float a, float b) {
    return __builtin_amdgcn_perm(__float_as_uint(b), __float_as_uint(a), 0x07060302u);
}
__device__ __forceinline__ void load_lds16(const void* g, void* l) {
    __builtin_amdgcn_global_load_lds(
        (const __attribute__((address_space(1))) void*)g,
        (__attribute__((address_space(3))) void*)l, 16, 0, 0);
}

// ---- dtype detection (fp32 buffers: random halfwords -> wild exponents)
__global__ void detect_kernel(const void* x, int* flag) {
    const unsigned short* p = (const unsigned short*)x;
    int t = threadIdx.x;
    int cnt = 0;
    for (int i = 0; i < 4; ++i) {
        unsigned short u = p[t * 4 + i];
        int e = (u >> 7) & 0xFF;
        if (e >= 140) cnt++;
    }
    for (int off = 32; off > 0; off >>= 1) cnt += __shfl_down(cnt, off, 64);
    if (t == 0) *flag = (cnt > 16) ? 1 : 0;   // 1 = fp32, 0 = bf16
}

// ---- only needed when input fp32: x -> xb (bf16)
__global__ __launch_bounds__(256) void conv_x_kernel(const void* __restrict__ x,
        unsigned short* __restrict__ xb, const int* __restrict__ flag) {
    if (*flag == 0) return;
    int i = (blockIdx.x * 256 + threadIdx.x) * 4;
    float4 v = *(const float4*)((const float*)x + i);
    ushort4 u = { f_to_bf16(v.x), f_to_bf16(v.y), f_to_bf16(v.z), f_to_bf16(v.w) };
    *(ushort4*)(xb + i) = u;
}

// ---- weights [K][N] -> Wt bf16 [mat*512 + n][k]
__global__ __launch_bounds__(256) void conv_wt_kernel(
        const void* W0, const void* W1, const void* W2, const void* W3,
        unsigned short* __restrict__ Wt, const int* __restrict__ flag) {
    __shared__ float T[64][65];
    int tid = threadIdx.x;
    int kt = blockIdx.x, nt = blockIdx.y, mat = blockIdx.z;
    const void* src = (mat == 0) ? W0 : (mat == 1) ? W1 : (mat == 2) ? W2 : W3;
    int fp32 = *flag;
    for (int ii = 0; ii < 4; ++ii) {
        int idx = tid + ii * 256;
        int i = idx >> 4, j = (idx & 15) * 4;
        size_t g = (size_t)(kt * 64 + i) * 512 + nt * 64 + j;
        if (fp32) {
            float4 v = *(const float4*)((const float*)src + g);
            T[i][j] = v.x; T[i][j+1] = v.y; T[i][j+2] = v.z; T[i][j+3] = v.w;
        } else {
            ushort4 u = *(const ushort4*)((const unsigned short*)src + g);
            T[i][j] = bf16_to_f(u.x); T[i][j+1] = bf16_to_f(u.y);
            T[i][j+2] = bf16_to_f(u.z); T[i][j+3] = bf16_to_f(u.w);
        }
    }
    __syncthreads();
    for (int ii = 0; ii < 2; ++ii) {
        int idx = tid + ii * 256;
        int j = idx >> 3, ch = idx & 7;
        unsigned short pk[8];
        for (int t = 0; t < 8; ++t) pk[t] = f_to_bf16(T[ch * 8 + t][j]);
        *(bf16x8*)&Wt[(size_t)(mat * 512 + nt * 64 + j) * 512 + kt * 64 + ch * 8] = *(bf16x8*)pk;
    }
}

// ---- 6 small vectors -> bias_all fp32 [6][512]: bq,bk,bv,bo,gamma,beta
__global__ __launch_bounds__(256) void conv_small_kernel(
        const void* b0, const void* b1, const void* b2, const void* b3,
        const void* b4, const void* b5, float* __restrict__ dst, const int* __restrict__ flag) {
    int idx = blockIdx.x * 256 + threadIdx.x;
    int mat = idx >> 9, off = idx & 511;
    const void* src = (mat == 0) ? b0 : (mat == 1) ? b1 : (mat == 2) ? b2 :
                      (mat == 3) ? b3 : (mat == 4) ? b4 : b5;
    float v;
    if (*flag) v = ((const float*)src)[off];
    else       v = bf16_to_f(((const unsigned short*)src)[off]);
    dst[idx] = v;
}

// ---- MFMA GEMM: C = A * Bt^T + bias, 128x128x64 tiles, 2-phase double-buffered.
// Per K-step: vmcnt(0)+barrier (buf[cur] landed, cur^1 readers done), then
// STAGE(cur^1, next k) in flight during compute(cur). LDS = 64KB (2 bufs).
// If VtOut != null, cols >= 1024 (V block of fused QKV) are written TRANSPOSED
// to VtOut[bh][d][seq] (bf16). XCD-aware block swizzle (grid %8==0 both uses).
template <typename OutT>
__global__ __launch_bounds__(256) void gemm_mfma_kernel(
        const unsigned short* __restrict__ A_conv, const unsigned short* __restrict__ A_raw,
        const int* __restrict__ flag,
        const unsigned short* __restrict__ Bt,
        const float* __restrict__ bias, OutT* __restrict__ C, int ldc, int scale_cols,
        unsigned short* __restrict__ VtOut) {
    __shared__ __align__(16) unsigned short smemg[2][2][128 * 64];  // [buf][A/B] 64KB
    const unsigned short* A = (*flag) ? A_conv : A_raw;
    int tid = threadIdx.x;
    int wave = tid >> 6, lane = tid & 63;
    int l15 = lane & 15, quad = lane >> 4;

    int lin = blockIdx.x + gridDim.x * blockIdx.y;
    int nwg = gridDim.x * gridDim.y;
    int bx, by;
    if (nwg & 7) { bx = blockIdx.x; by = blockIdx.y; }
    else {
        int t = (lin & 7) * (nwg >> 3) + (lin >> 3);
        bx = t % gridDim.x; by = t / gridDim.x;
    }
    int m0 = by * 128, n0 = bx * 128;
    int wm = (wave & 1) * 64, wn = (wave >> 1) * 64;

    int rt = wave * 32 + (lane >> 3);
    int ch = (lane & 7) ^ ((lane >> 3) & 7);
    const unsigned short* ag = A  + (size_t)(m0 + rt) * 512 + ch * 8;
    const unsigned short* bg = Bt + (size_t)(n0 + rt) * 512 + ch * 8;

    f32x4 acc[4][4];
    for (int i = 0; i < 4; ++i) for (int j = 0; j < 4; ++j) acc[i][j] = (f32x4){0.f,0.f,0.f,0.f};

#define GSTAGE(buf, k0) do {                                                      \
        unsigned short* Atb = &smemg[buf][0][0];                                  \
        unsigned short* Bsb = &smemg[buf][1][0];                                  \
        _Pragma("unroll")                                                         \
        for (int j = 0; j < 4; ++j) {                                             \
            load_lds16(ag + (size_t)(j * 8) * 512 + (k0), &Atb[(wave * 32 + j * 8) * 64]); \
            load_lds16(bg + (size_t)(j * 8) * 512 + (k0), &Bsb[(wave * 32 + j * 8) * 64]); \
        }                                                                         \
    } while (0)

    GSTAGE(0, 0);   // prologue

    for (int s = 0; s < 8; ++s) {
        int cur = s & 1;
        asm volatile("s_waitcnt vmcnt(0)" ::: "memory");
        __builtin_amdgcn_sched_barrier(0);
        asm volatile("s_barrier" ::: "memory");
        __builtin_amdgcn_sched_barrier(0);
        if (s + 1 < 8) GSTAGE(cur ^ 1, (s + 1) * 64);   // in flight during compute

        const unsigned short* At = &smemg[cur][0][0];
        const unsigned short* Bs = &smemg[cur][1][0];
        #pragma unroll
        for (int ks = 0; ks < 2; ++ks) {
            bf16x8 a[4], b[4];
            #pragma unroll
            for (int f = 0; f < 4; ++f) {
                int pc = ((ks * 4 + quad) ^ (l15 & 7)) * 8;
                a[f] = *(const bf16x8*)&At[(wm + f * 16 + l15) * 64 + pc];
                b[f] = *(const bf16x8*)&Bs[(wn + f * 16 + l15) * 64 + pc];
            }
            #pragma unroll
            for (int fm = 0; fm < 4; ++fm)
                #pragma unroll
                for (int fn = 0; fn < 4; ++fn)
                    acc[fm][fn] = __builtin_amdgcn_mfma_f32_16x16x32_bf16(a[fm], b[fn], acc[fm][fn], 0, 0, 0);
        }
        __builtin_amdgcn_sched_barrier(0);
    }
#undef GSTAGE

    #pragma unroll
    for (int fm = 0; fm < 4; ++fm) {
        #pragma unroll
        for (int fn = 0; fn < 4; ++fn) {
            int col = n0 + wn + fn * 16 + l15;
            float bia = bias[col];
            float sc = (col < scale_cols) ? QSCALE : 1.f;
            int rowbase = m0 + wm + fm * 16 + quad * 4;
            float v0 = (acc[fm][fn][0] + bia) * sc;
            float v1 = (acc[fm][fn][1] + bia) * sc;
            float v2 = (acc[fm][fn][2] + bia) * sc;
            float v3 = (acc[fm][fn][3] + bia) * sc;
            if (VtOut && col >= 1024) {
                int hd = col - 1024;
                int bh = (rowbase >> 12) * 8 + (hd >> 6);
                int d  = hd & 63;
                ushort4 pk = { f_to_bf16(v0), f_to_bf16(v1), f_to_bf16(v2), f_to_bf16(v3) };
                *(ushort4*)&VtOut[((size_t)(bh * 64 + d)) * SEQ + (rowbase & 4095)] = pk;
            } else {
                if constexpr (sizeof(OutT) == 2) {
                    C[(size_t)(rowbase + 0) * ldc + col] = (OutT)f_to_bf16(v0);
                    C[(size_t)(rowbase + 1) * ldc + col] = (OutT)f_to_bf16(v1);
                    C[(size_t)(rowbase + 2) * ldc + col] = (OutT)f_to_bf16(v2);
                    C[(size_t)(rowbase + 3) * ldc + col] = (OutT)f_to_bf16(v3);
                } else {
                    C[(size_t)(rowbase + 0) * ldc + col] = v0;
                    C[(size_t)(rowbase + 1) * ldc + col] = v1;
                    C[(size_t)(rowbase + 2) * ldc + col] = v2;
                    C[(size_t)(rowbase + 3) * ldc + col] = v3;
                }
            }
        }
    }
}

// ---- MFMA flash attention, 2-phase double-buffered. Block = 64 q, 4 waves,
// 2q x 2k split. KVBLK = 64. Ks[2] @ {0,8K}, Vs[2] @ {16K,24K}. Per iter:
// vmcnt(0)+barrier, STAGE(next) in flight during compute(cur).
// S^T = K·Q^T -> exp2 -> v_perm pack -> K16 PV. setprio(1) around MFMA clusters.
// Epilogue normalizes by 1/l, writes bf16.
__global__ __launch_bounds__(256, 4) void attn_kernel(
        const unsigned short* __restrict__ QKV, const unsigned short* __restrict__ Vt,
        unsigned short* __restrict__ Ab) {
    __shared__ __align__(16) unsigned char smem[32768];
    float* Ored = (float*)smem;                 // epilogue [4 w][16 q][64 d] (16KB)
    float* Lred = (float*)(smem + 16384);       // epilogue [4 w][2 t][16 q] (512B)

    int tid = threadIdx.x;
    int wave = tid >> 6, lane = tid & 63;
    int l15 = lane & 15, quad = lane >> 4;
    int qh = wave >> 1, kh = wave & 1;
    // grid 1024 = 8 xcd * 128 slots; grp = xcd + 8*(slot>>6); qt = slot&63
    int lin = blockIdx.x;
    int xcd = lin & 7, slot = lin >> 3;
    int grp = xcd + 8 * (slot >> 6);      // 16 (b,h) groups, 2 per XCD
    int qt = slot & 63;
    int h = grp & 7, b = grp >> 3;
    int bh = b * HEADS + h;
    size_t qrow0 = (size_t)b * SEQ + qt * 64;

    // Q B-frags (n = q = l15, k = d): rows qh*32 + t*16 + l15. Pre-scaled by QSCALE.
    bf16x8 aq[2][2];
    #pragma unroll
    for (int t = 0; t < 2; ++t) {
        const unsigned short* qp = &QKV[(qrow0 + qh * 32 + t * 16 + l15) * 1536 + h * 64];
        aq[t][0] = *(const bf16x8*)&qp[quad * 8];
        aq[t][1] = *(const bf16x8*)&qp[32 + quad * 8];
    }
    f32x4 o[2][4];     // [t][db]: O[q = qh*32+t*16+quad*4+r][d = db*16+l15], partial over kh
    #pragma unroll
    for (int t = 0; t < 2; ++t)
        #pragma unroll
        for (int db = 0; db < 4; ++db) o[t][db] = (f32x4){0.f, 0.f, 0.f, 0.f};
    float lp[2] = {0.f, 0.f};   // per-lane: q = l15, summed over this lane's kcols

    // staging base pointers. Per gload_lds instr: 1KB = 8 rows x 128B.
    // lane: row offset = lane>>3, 16B chunk = lane&7, XOR-swizzled by row&7.
    int r8 = lane >> 3;
    int kch = (lane & 7) ^ (r8 & 7);
    const unsigned short* kg = &QKV[((size_t)b * SEQ + r8) * 1536 + 512 + h * 64 + kch * 8];
    const unsigned short* vg = &Vt[((size_t)bh * 64 + wave * 16 + r8) * SEQ + kch * 8];

#define STAGE(buf, kt2) do {                                                          \
        unsigned short* Ksb = (unsigned short*)(smem + (buf) * 8192);                 \
        unsigned short* Vsb = (unsigned short*)(smem + 16384 + (buf) * 8192);         \
        load_lds16(kg + (size_t)((kt2) * 64 + wave * 16) * 1536,                      \
                   &Ksb[(wave * 16) * 64]);                                           \
        load_lds16(kg + (size_t)((kt2) * 64 + wave * 16 + 8) * 1536,                  \
                   &Ksb[(wave * 16 + 8) * 64]);                                       \
        load_lds16(vg + (size_t)((kt2) * 64), &Vsb[(wave * 16) * 64]);                \
        load_lds16(vg + (size_t)((kt2) * 64) + (size_t)8 * SEQ,                       \
                   &Vsb[(wave * 16 + 8) * 64]);                                       \
    } while (0)

    STAGE(0, 0);   // prologue

    for (int kt = 0; kt < SEQ / 64; ++kt) {
        int cur = kt & 1;
        asm volatile("s_waitcnt vmcnt(0)" ::: "memory");
        __builtin_amdgcn_sched_barrier(0);
        asm volatile("s_barrier" ::: "memory");
        __builtin_amdgcn_sched_barrier(0);
        if (kt + 1 < SEQ / 64) STAGE(cur ^ 1, kt + 1);   // overlaps with compute below

        const unsigned short* Ksc = (const unsigned short*)(smem + cur * 8192);
        const unsigned short* Vsc = (const unsigned short*)(smem + 16384 + cur * 8192);
        #pragma unroll
        for (int nb = 0; nb < 2; ++nb) {
            int kc = kh * 32 + nb * 16;              // wave's kcol tile base in 64-tile
            int krow = kc + l15;
            int key = krow & 7;
            bf16x8 kA0 = *(const bf16x8*)&Ksc[krow * 64 + (quad ^ key) * 8];
            bf16x8 kA1 = *(const bf16x8*)&Ksc[krow * 64 + ((4 + quad) ^ key) * 8];
            // V B-frags (k = kcol = quad*4+j, n = d = db*16+l15): 8B reads
            bf16x4 bv[4];
            #pragma unroll
            for (int db = 0; db < 4; ++db) {
                int d = db * 16 + l15;
                int c16 = (kc >> 3) + (quad >> 1);   // 16B chunk index (0..7)
                int sub = (quad & 1) * 4;
                bv[db] = *(const bf16x4*)&Vsc[d * 64 + ((c16 ^ (d & 7)) * 8) + sub];
            }
            #pragma unroll
            for (int t = 0; t < 2; ++t) {
                f32x4 sv = {0.f, 0.f, 0.f, 0.f};
                __builtin_amdgcn_s_setprio(1);
                sv = __builtin_amdgcn_mfma_f32_16x16x32_bf16(kA0, aq[t][0], sv, 0, 0, 0);
                sv = __builtin_amdgcn_mfma_f32_16x16x32_bf16(kA1, aq[t][1], sv, 0, 0, 0);
                __builtin_amdgcn_s_setprio(0);
                float p0 = __builtin_amdgcn_exp2f(sv[0]);
                float p1 = __builtin_amdgcn_exp2f(sv[1]);
                float p2 = __builtin_amdgcn_exp2f(sv[2]);
                float p3 = __builtin_amdgcn_exp2f(sv[3]);
                lp[t] += (p0 + p1) + (p2 + p3);
                union { unsigned int u[2]; bf16x4 v; } ap;
                ap.u[0] = pack_bf16_trunc(p0, p1);
                ap.u[1] = pack_bf16_trunc(p2, p3);
                __builtin_amdgcn_s_setprio(1);
                #pragma unroll
                for (int db = 0; db < 4; ++db)
                    o[t][db] = MFMA_K16(ap.v, bv[db], o[t][db]);
                __builtin_amdgcn_s_setprio(0);
            }
        }
        __builtin_amdgcn_sched_barrier(0);
    }
#undef STAGE

    // ---- epilogue: l over quads (shfl); O/l over kh pairs via LDS; write bf16.
    __syncthreads();
    #pragma unroll
    for (int t = 0; t < 2; ++t) {
        float v = lp[t];
        v += __shfl_xor(v, 16, 64);
        v += __shfl_xor(v, 32, 64);
        if (quad == 0) Lred[(wave * 2 + t) * 16 + l15] = v;
    }
    __syncthreads();
    float* myO = Ored + wave * (16 * 64);
    #pragma unroll
    for (int t = 0; t < 2; ++t) {
        #pragma unroll
        for (int db = 0; db < 4; ++db)
            #pragma unroll
            for (int r = 0; r < 4; ++r)
                myO[(quad * 4 + r) * 64 + db * 16 + l15] = o[t][db][r];
        __syncthreads();
        {
            int q_l = tid >> 3;              // 0..31
            int dg = tid & 7;
            int qh2 = q_l >> 4, qq = q_l & 15;
            const float* r0 = Ored + (qh2 * 2 + 0) * (16 * 64) + qq * 64 + dg * 8;
            const float* r1 = Ored + (qh2 * 2 + 1) * (16 * 64) + qq * 64 + dg * 8;
            float4 a0 = *(const float4*)&r0[0];
            float4 a1 = *(const float4*)&r0[4];
            float4 c0 = *(const float4*)&r1[0];
            float4 c1 = *(const float4*)&r1[4];
            float lt = Lred[((qh2 * 2 + 0) * 2 + t) * 16 + qq] +
                       Lred[((qh2 * 2 + 1) * 2 + t) * 16 + qq];
            float inv = 1.f / lt;
            size_t row = qrow0 + qh2 * 32 + t * 16 + qq;
            unsigned short* dst = &Ab[row * EMB + h * 64 + dg * 8];
            ushort4 lo = { f_to_bf16((a0.x + c0.x) * inv), f_to_bf16((a0.y + c0.y) * inv),
                           f_to_bf16((a0.z + c0.z) * inv), f_to_bf16((a0.w + c0.w) * inv) };
            ushort4 hi = { f_to_bf16((a1.x + c1.x) * inv), f_to_bf16((a1.y + c1.y) * inv),
                           f_to_bf16((a1.z + c1.z) * inv), f_to_bf16((a1.w + c1.w) * inv) };
            *(ushort4*)&dst[0] = lo;
            *(ushort4*)&dst[4] = hi;
        }
        __syncthreads();
    }
}

// ---- y = x + P; LayerNorm -> out. 4 rows per block (1 wave each).
__global__ __launch_bounds__(256) void ln_kernel(
        const float* __restrict__ xf, const unsigned short* __restrict__ xraw,
        const unsigned short* __restrict__ P,
        const float* __restrict__ gamma, const float* __restrict__ beta,
        void* __restrict__ out, const int* __restrict__ flag) {
    int row = blockIdx.x * 4 + (threadIdx.x >> 6);
    int t = threadIdx.x & 63;
    int fp32 = *flag;
    float v[8];
    float s = 0.f, ss = 0.f;
    const unsigned short* pp = &P[(size_t)row * EMB + t * 8];
    ushort4 p0 = *(const ushort4*)&pp[0];
    ushort4 p1 = *(const ushort4*)&pp[4];
    float pv[8] = { bf16_to_f(p0.x), bf16_to_f(p0.y), bf16_to_f(p0.z), bf16_to_f(p0.w),
                    bf16_to_f(p1.x), bf16_to_f(p1.y), bf16_to_f(p1.z), bf16_to_f(p1.w) };
    if (fp32) {
        const float* xp = &xf[(size_t)row * EMB + t * 8];
        for (int i = 0; i < 8; i += 4) {
            float4 x4 = *(const float4*)&xp[i];
            v[i] = x4.x + pv[i]; v[i+1] = x4.y + pv[i+1];
            v[i+2] = x4.z + pv[i+2]; v[i+3] = x4.w + pv[i+3];
        }
    } else {
        const unsigned short* xp = &xraw[(size_t)row * EMB + t * 8];
        ushort4 x0 = *(const ushort4*)&xp[0];
        ushort4 x1 = *(const ushort4*)&xp[4];
        v[0] = bf16_to_f(x0.x) + pv[0]; v[1] = bf16_to_f(x0.y) + pv[1];
        v[2] = bf16_to_f(x0.z) + pv[2]; v[3] = bf16_to_f(x0.w) + pv[3];
        v[4] = bf16_to_f(x1.x) + pv[4]; v[5] = bf16_to_f(x1.y) + pv[5];
        v[6] = bf16_to_f(x1.z) + pv[6]; v[7] = bf16_to_f(x1.w) + pv[7];
    }
    for (int i = 0; i < 8; ++i) { s += v[i]; ss += v[i] * v[i]; }
    for (int off = 32; off > 0; off >>= 1) {
        s  += __shfl_xor(s, off, 64);
        ss += __shfl_xor(ss, off, 64);
    }
    float mu = s * (1.f / 512.f);
    float var = ss * (1.f / 512.f) - mu * mu;
    float rs = rsqrtf(var + 1e-5f);
    for (int i = 0; i < 8; ++i) {
        int col = t * 8 + i;
        float y = (v[i] - mu) * rs * gamma[col] + beta[col];
        if (fp32) ((float*)out)[(size_t)row * EMB + col] = y;
        else      ((__hip_bfloat16*)out)[(size_t)row * EMB + col] = __float2bfloat16(y);
    }
}

extern "C" void kernel_launch(void* const* d_in, const int* in_sizes, int n_in,
                              void* d_out, int out_size, void* d_ws, size_t ws_size,
                              hipStream_t stream) {
    char* ws = (char*)d_ws;
    int* flag = (int*)ws;
    char* p = ws + 256;
    float* bias_all = (float*)p;       p += 6 * 512 * 4;
    unsigned short* Wt   = (unsigned short*)p; p += (size_t)2048 * 512 * 2;  // 2MB
    unsigned short* QKVb = (unsigned short*)p; p += (size_t)ROWS * 1536 * 2; // 24MB
    unsigned short* Vt   = (unsigned short*)p; p += (size_t)16 * HD * SEQ * 2; // 8MB
    // shared region: xb (conv_x -> QKV gemm) then Ab (attn -> O-proj)
    unsigned short* xb = (unsigned short*)p;
    unsigned short* Ab = (unsigned short*)p;   p += (size_t)ROWS * EMB * 2;  // 8MB
    unsigned short* Pb = (unsigned short*)p;   p += (size_t)ROWS * EMB * 2;  // 8MB

    detect_kernel<<<1, 64, 0, stream>>>(d_in[0], flag);

    conv_x_kernel<<<ROWS * EMB / 1024, 256, 0, stream>>>(d_in[0], xb, flag);
    conv_wt_kernel<<<dim3(8, 8, 4), 256, 0, stream>>>(d_in[1], d_in[3], d_in[5], d_in[7], Wt, flag);
    conv_small_kernel<<<12, 256, 0, stream>>>(d_in[2], d_in[4], d_in[6], d_in[8], d_in[9], d_in[10],
                                              bias_all, flag);

    // fused QKV: N=1536; Q cols pre-scaled by QSCALE; V cols written transposed to Vt
    gemm_mfma_kernel<unsigned short><<<dim3(12, 64), 256, 0, stream>>>(
        xb, (const unsigned short*)d_in[0], flag, Wt, bias_all, QKVb, 1536, 512, Vt);

    attn_kernel<<<dim3(1024), 256, 0, stream>>>(QKVb, Vt, Ab);

    // O-proj -> bf16
    gemm_mfma_kernel<unsigned short><<<dim3(4, 64), 256, 0, stream>>>(
        Ab, Ab, flag, Wt + (size_t)1536 * 512, bias_all + 1536, Pb, 512, 0,
        (unsigned short*)nullptr);

    ln_kernel<<<ROWS / 4, 256, 0, stream>>>((const float*)d_in[0],
                                            (const unsigned short*)d_in[0], Pb,
                                            bias_all + 4 * 512, bias_all + 5 * 512, d_out, flag);
}

// Round 5
// 220.483 us; speedup vs baseline: 1.6809x; 1.0793x over previous
//
#include <hip/hip_runtime.h>
#include <hip/hip_bf16.h>

// SelfAttention B=2,N=4096,E=512,H=8,D=64 — Round 15:
// R14 post-mortem: attn issue-bound; PV via K16 MFMA = 33us of 50us MFMA busy
// (K16 runs at half rate). R15:
//  (a) attn PV K16 -> K32: K rows PERMUTED at staging (LDS row nb*16+g*4+e <-
//      global kcol 8g+4nb+e, folded into per-lane gload address, zero runtime
//      cost). Packed S^T outputs [nb0 e0..3, nb1 e0..3] then form the K32
//      A-frag directly; V B-frag = natural-order b128. 16 K16 -> 8 K32 /iter.
//  (b) detect_kernel removed (inline wave-uniform detect); conv_x+conv_wt+
//      conv_small fused into prep_kernel. 8 -> 5 dispatches.

#define ROWS 8192
#define EMB  512
#define SEQ  4096
#define HEADS 8
#define HD   64
#define QSCALE 0.18033688011112042f   // 0.125 * log2(e)

typedef __attribute__((ext_vector_type(8))) short bf16x8;
typedef __attribute__((ext_vector_type(4))) short bf16x4;
typedef __attribute__((ext_vector_type(4))) float f32x4;

__device__ __forceinline__ float bf16_to_f(unsigned short u) {
    union { unsigned int i; float f; } v; v.i = ((unsigned int)u) << 16; return v.f;
}
__device__ __forceinline__ unsigned short f_to_bf16(float f) {
    union { __hip_bfloat16 h; unsigned short u; } v; v.h = __float2bfloat16(f); return v.u;
}
// low16 = hi16(a), high16 = hi16(b) — single v_perm_b32
__device__ __forceinline__ unsigned int pack_bf16_trunc(float a, float b) {
    return __builtin_amdgcn_perm(__float_as_uint(b), __float_as_uint(a), 0x07060302u);
}
__device__ __forceinline__ void load_lds16(const void* g, void* l) {
    __builtin_amdgcn_global_load_lds(
        (const __attribute__((address_space(1))) void*)g,
        (__attribute__((address_space(3))) void*)l, 16, 0, 0);
}

// ---- inline dtype detection: fp32 buffers have wild "exponents" in halfwords.
// Reads the same fixed 256 halfwords in every block -> uniform result.
__device__ __forceinline__ int detect_fp32(const void* x) {
    const unsigned short* p = (const unsigned short*)x;
    int t = threadIdx.x & 63;
    int cnt = 0;
    #pragma unroll
    for (int i = 0; i < 4; ++i) {
        unsigned short u = p[t * 4 + i];
        int e = (u >> 7) & 0xFF;
        cnt += (e >= 140) ? 1 : 0;
    }
    #pragma unroll
    for (int off = 32; off > 0; off >>= 1) cnt += __shfl_xor(cnt, off, 64);
    return cnt > 16;
}

// ---- fused prep: [0,4096) conv_x | [4096,4352) conv_wt | [4352,4364) conv_small
__global__ __launch_bounds__(256) void prep_kernel(
        const void* __restrict__ x, unsigned short* __restrict__ xb,
        const void* W0, const void* W1, const void* W2, const void* W3,
        unsigned short* __restrict__ Wt,
        const void* b0, const void* b1, const void* b2, const void* b3,
        const void* b4, const void* b5, float* __restrict__ bias_all) {
    int fp32 = detect_fp32(x);
    int bid = blockIdx.x;
    int tid = threadIdx.x;
    if (bid < 4096) {                       // ---- conv_x: x -> xb (bf16)
        if (!fp32) return;
        int i = (bid * 256 + tid) * 4;
        float4 v = *(const float4*)((const float*)x + i);
        ushort4 u = { f_to_bf16(v.x), f_to_bf16(v.y), f_to_bf16(v.z), f_to_bf16(v.w) };
        *(ushort4*)(xb + i) = u;
    } else if (bid < 4352) {                // ---- conv_wt: W[K][N] -> Wt[n][k]
        __shared__ float T[64][65];
        int idx0 = bid - 4096;
        int kt = idx0 & 7, nt = (idx0 >> 3) & 7, mat = idx0 >> 6;
        const void* src = (mat == 0) ? W0 : (mat == 1) ? W1 : (mat == 2) ? W2 : W3;
        for (int ii = 0; ii < 4; ++ii) {
            int idx = tid + ii * 256;
            int i = idx >> 4, j = (idx & 15) * 4;
            size_t g = (size_t)(kt * 64 + i) * 512 + nt * 64 + j;
            if (fp32) {
                float4 v = *(const float4*)((const float*)src + g);
                T[i][j] = v.x; T[i][j+1] = v.y; T[i][j+2] = v.z; T[i][j+3] = v.w;
            } else {
                ushort4 u = *(const ushort4*)((const unsigned short*)src + g);
                T[i][j] = bf16_to_f(u.x); T[i][j+1] = bf16_to_f(u.y);
                T[i][j+2] = bf16_to_f(u.z); T[i][j+3] = bf16_to_f(u.w);
            }
        }
        __syncthreads();
        for (int ii = 0; ii < 2; ++ii) {
            int idx = tid + ii * 256;
            int j = idx >> 3, ch = idx & 7;
            unsigned short pk[8];
            for (int t = 0; t < 8; ++t) pk[t] = f_to_bf16(T[ch * 8 + t][j]);
            *(bf16x8*)&Wt[(size_t)(mat * 512 + nt * 64 + j) * 512 + kt * 64 + ch * 8] = *(bf16x8*)pk;
        }
    } else {                                // ---- conv_small: 6 vecs -> bias_all
        int idx = (bid - 4352) * 256 + tid;
        int mat = idx >> 9, off = idx & 511;
        const void* src = (mat == 0) ? b0 : (mat == 1) ? b1 : (mat == 2) ? b2 :
                          (mat == 3) ? b3 : (mat == 4) ? b4 : b5;
        float v;
        if (fp32) v = ((const float*)src)[off];
        else      v = bf16_to_f(((const unsigned short*)src)[off]);
        bias_all[idx] = v;
    }
}

// ---- MFMA GEMM: C = A * Bt^T + bias, 128x128x64 tiles, 2-phase double-buffered.
// A = fp32-detected ? A_conv : A_raw (detection inline from A_raw's first bytes;
// for O-proj both pointers are identical so the branch is moot).
// If VtOut != null, cols >= 1024 (V block of fused QKV) are written TRANSPOSED
// to VtOut[bh][d][seq] (bf16). XCD-aware block swizzle (grid %8==0 both uses).
template <typename OutT>
__global__ __launch_bounds__(256) void gemm_mfma_kernel(
        const unsigned short* __restrict__ A_conv, const unsigned short* __restrict__ A_raw,
        const unsigned short* __restrict__ Bt,
        const float* __restrict__ bias, OutT* __restrict__ C, int ldc, int scale_cols,
        unsigned short* __restrict__ VtOut) {
    __shared__ __align__(16) unsigned short smemg[2][2][128 * 64];  // [buf][A/B] 64KB
    const unsigned short* A = detect_fp32(A_raw) ? A_conv : A_raw;
    int tid = threadIdx.x;
    int wave = tid >> 6, lane = tid & 63;
    int l15 = lane & 15, quad = lane >> 4;

    int lin = blockIdx.x + gridDim.x * blockIdx.y;
    int nwg = gridDim.x * gridDim.y;
    int bx, by;
    if (nwg & 7) { bx = blockIdx.x; by = blockIdx.y; }
    else {
        int t = (lin & 7) * (nwg >> 3) + (lin >> 3);
        bx = t % gridDim.x; by = t / gridDim.x;
    }
    int m0 = by * 128, n0 = bx * 128;
    int wm = (wave & 1) * 64, wn = (wave >> 1) * 64;

    int rt = wave * 32 + (lane >> 3);
    int ch = (lane & 7) ^ ((lane >> 3) & 7);
    const unsigned short* ag = A  + (size_t)(m0 + rt) * 512 + ch * 8;
    const unsigned short* bg = Bt + (size_t)(n0 + rt) * 512 + ch * 8;

    f32x4 acc[4][4];
    for (int i = 0; i < 4; ++i) for (int j = 0; j < 4; ++j) acc[i][j] = (f32x4){0.f,0.f,0.f,0.f};

#define GSTAGE(buf, k0) do {                                                      \
        unsigned short* Atb = &smemg[buf][0][0];                                  \
        unsigned short* Bsb = &smemg[buf][1][0];                                  \
        _Pragma("unroll")                                                         \
        for (int j = 0; j < 4; ++j) {                                             \
            load_lds16(ag + (size_t)(j * 8) * 512 + (k0), &Atb[(wave * 32 + j * 8) * 64]); \
            load_lds16(bg + (size_t)(j * 8) * 512 + (k0), &Bsb[(wave * 32 + j * 8) * 64]); \
        }                                                                         \
    } while (0)

    GSTAGE(0, 0);   // prologue

    for (int s = 0; s < 8; ++s) {
        int cur = s & 1;
        asm volatile("s_waitcnt vmcnt(0)" ::: "memory");
        __builtin_amdgcn_sched_barrier(0);
        asm volatile("s_barrier" ::: "memory");
        __builtin_amdgcn_sched_barrier(0);
        if (s + 1 < 8) GSTAGE(cur ^ 1, (s + 1) * 64);   // in flight during compute

        const unsigned short* At = &smemg[cur][0][0];
        const unsigned short* Bs = &smemg[cur][1][0];
        #pragma unroll
        for (int ks = 0; ks < 2; ++ks) {
            bf16x8 a[4], b[4];
            #pragma unroll
            for (int f = 0; f < 4; ++f) {
                int pc = ((ks * 4 + quad) ^ (l15 & 7)) * 8;
                a[f] = *(const bf16x8*)&At[(wm + f * 16 + l15) * 64 + pc];
                b[f] = *(const bf16x8*)&Bs[(wn + f * 16 + l15) * 64 + pc];
            }
            #pragma unroll
            for (int fm = 0; fm < 4; ++fm)
                #pragma unroll
                for (int fn = 0; fn < 4; ++fn)
                    acc[fm][fn] = __builtin_amdgcn_mfma_f32_16x16x32_bf16(a[fm], b[fn], acc[fm][fn], 0, 0, 0);
        }
        __builtin_amdgcn_sched_barrier(0);
    }
#undef GSTAGE

    #pragma unroll
    for (int fm = 0; fm < 4; ++fm) {
        #pragma unroll
        for (int fn = 0; fn < 4; ++fn) {
            int col = n0 + wn + fn * 16 + l15;
            float bia = bias[col];
            float sc = (col < scale_cols) ? QSCALE : 1.f;
            int rowbase = m0 + wm + fm * 16 + quad * 4;
            float v0 = (acc[fm][fn][0] + bia) * sc;
            float v1 = (acc[fm][fn][1] + bia) * sc;
            float v2 = (acc[fm][fn][2] + bia) * sc;
            float v3 = (acc[fm][fn][3] + bia) * sc;
            if (VtOut && col >= 1024) {
                int hd = col - 1024;
                int bh = (rowbase >> 12) * 8 + (hd >> 6);
                int d  = hd & 63;
                ushort4 pk = { f_to_bf16(v0), f_to_bf16(v1), f_to_bf16(v2), f_to_bf16(v3) };
                *(ushort4*)&VtOut[((size_t)(bh * 64 + d)) * SEQ + (rowbase & 4095)] = pk;
            } else {
                if constexpr (sizeof(OutT) == 2) {
                    C[(size_t)(rowbase + 0) * ldc + col] = (OutT)f_to_bf16(v0);
                    C[(size_t)(rowbase + 1) * ldc + col] = (OutT)f_to_bf16(v1);
                    C[(size_t)(rowbase + 2) * ldc + col] = (OutT)f_to_bf16(v2);
                    C[(size_t)(rowbase + 3) * ldc + col] = (OutT)f_to_bf16(v3);
                } else {
                    C[(size_t)(rowbase + 0) * ldc + col] = v0;
                    C[(size_t)(rowbase + 1) * ldc + col] = v1;
                    C[(size_t)(rowbase + 2) * ldc + col] = v2;
                    C[(size_t)(rowbase + 3) * ldc + col] = v3;
                }
            }
        }
    }
}

// ---- MFMA flash attention, 2-phase double-buffered, K32 PV.
// Block = 64 q, 4 waves, 2q x 2k split; KVBLK = 64. Ks[2]@{0,8K}, Vs[2]@{16K,24K}.
// K rows are PERMUTED at staging: within each 32-row group, LDS row
// r = nb*16 + g*4 + e holds global kcol c = 8g + 4nb + e. The two 16x16 S^T
// tiles then give each lane (quad g) P for kcols 8g+{0..7} in pack order
// [nb0 e0..e3, nb1 e0..e3] = K32 A-frag k = 8g+j. V stays natural order:
// B-frag = one b128 per 16-d block. Softmax is kcol-permutation-invariant.
__global__ __launch_bounds__(256, 4) void attn_kernel(
        const unsigned short* __restrict__ QKV, const unsigned short* __restrict__ Vt,
        unsigned short* __restrict__ Ab) {
    __shared__ __align__(16) unsigned char smem[32768];
    float* Ored = (float*)smem;                 // epilogue [4 w][16 q][64 d] (16KB)
    float* Lred = (float*)(smem + 16384);       // epilogue [4 w][2 t][16 q] (512B)

    int tid = threadIdx.x;
    int wave = tid >> 6, lane = tid & 63;
    int l15 = lane & 15, quad = lane >> 4;
    int qh = wave >> 1, kh = wave & 1;
    // grid 1024 = 8 xcd * 128 slots; grp = xcd + 8*(slot>>6); qt = slot&63
    int lin = blockIdx.x;
    int xcd = lin & 7, slot = lin >> 3;
    int grp = xcd + 8 * (slot >> 6);      // 16 (b,h) groups, 2 per XCD
    int qt = slot & 63;
    int h = grp & 7, b = grp >> 3;
    int bh = b * HEADS + h;
    size_t qrow0 = (size_t)b * SEQ + qt * 64;

    // Q B-frags (n = q = l15, k = d): rows qh*32 + t*16 + l15. Pre-scaled by QSCALE.
    bf16x8 aq[2][2];
    #pragma unroll
    for (int t = 0; t < 2; ++t) {
        const unsigned short* qp = &QKV[(qrow0 + qh * 32 + t * 16 + l15) * 1536 + h * 64];
        aq[t][0] = *(const bf16x8*)&qp[quad * 8];
        aq[t][1] = *(const bf16x8*)&qp[32 + quad * 8];
    }
    f32x4 o[2][4];     // [t][db]: O[q = qh*32+t*16+quad*4+r][d = db*16+l15], partial over kh
    #pragma unroll
    for (int t = 0; t < 2; ++t)
        #pragma unroll
        for (int db = 0; db < 4; ++db) o[t][db] = (f32x4){0.f, 0.f, 0.f, 0.f};
    float lp[2] = {0.f, 0.f};   // per-lane: q = l15, summed over this lane's kcols

    // staging. Per gload_lds: 1KB = 8 LDS rows x 128B; lane dest row = base + (lane>>3),
    // chunk = lane&7. Source chunk XOR-swizzled by dest row&7 (= lane>>3 & 7).
    // K source row runs through perm P: LDS row r -> global kcol
    //   P(r) = (r&32) | ((r>>2)&3)<<3 | ((r>>4)&1)<<2 | (r&3)
    int r8 = lane >> 3;
    int kch = (lane & 7) ^ (r8 & 7);
    int r0 = wave * 16 + r8;          // LDS row, first gload
    int r1 = wave * 16 + 8 + r8;      // LDS row, second gload
    int p0r = (r0 & 32) | (((r0 >> 2) & 3) << 3) | (((r0 >> 4) & 1) << 2) | (r0 & 3);
    int p1r = (r1 & 32) | (((r1 >> 2) & 3) << 3) | (((r1 >> 4) & 1) << 2) | (r1 & 3);
    const unsigned short* kg0 = &QKV[((size_t)b * SEQ + p0r) * 1536 + 512 + h * 64 + kch * 8];
    const unsigned short* kg1 = &QKV[((size_t)b * SEQ + p1r) * 1536 + 512 + h * 64 + kch * 8];
    const unsigned short* vg = &Vt[((size_t)bh * 64 + wave * 16 + r8) * SEQ + kch * 8];

#define STAGE(buf, kt2) do {                                                          \
        unsigned short* Ksb = (unsigned short*)(smem + (buf) * 8192);                 \
        unsigned short* Vsb = (unsigned short*)(smem + 16384 + (buf) * 8192);         \
        load_lds16(kg0 + (size_t)((kt2) * 64) * 1536, &Ksb[(wave * 16) * 64]);        \
        load_lds16(kg1 + (size_t)((kt2) * 64) * 1536, &Ksb[(wave * 16 + 8) * 64]);    \
        load_lds16(vg + (size_t)((kt2) * 64), &Vsb[(wave * 16) * 64]);                \
        load_lds16(vg + (size_t)((kt2) * 64) + (size_t)8 * SEQ,                       \
                   &Vsb[(wave * 16 + 8) * 64]);                                       \
    } while (0)

    STAGE(0, 0);   // prologue

    for (int kt = 0; kt < SEQ / 64; ++kt) {
        int cur = kt & 1;
        asm volatile("s_waitcnt vmcnt(0)" ::: "memory");
        __builtin_amdgcn_sched_barrier(0);
        asm volatile("s_barrier" ::: "memory");
        __builtin_amdgcn_sched_barrier(0);
        if (kt + 1 < SEQ / 64) STAGE(cur ^ 1, kt + 1);   // overlaps with compute below

        const unsigned short* Ksc = (const unsigned short*)(smem + cur * 8192);
        const unsigned short* Vsc = (const unsigned short*)(smem + 16384 + cur * 8192);

        // K A-frags: both 16x16 tiles of this wave's 32-kcol window (rows permuted)
        bf16x8 kA[2][2];
        #pragma unroll
        for (int nb = 0; nb < 2; ++nb) {
            int krow = kh * 32 + nb * 16 + l15;
            int key = krow & 7;
            kA[nb][0] = *(const bf16x8*)&Ksc[krow * 64 + (quad ^ key) * 8];
            kA[nb][1] = *(const bf16x8*)&Ksc[krow * 64 + ((4 + quad) ^ key) * 8];
        }
        // V B-frags (K32): k = quad*8+j = kcol offset (natural order), n = d
        bf16x8 bv8[4];
        #pragma unroll
        for (int db = 0; db < 4; ++db) {
            int d = db * 16 + l15;
            bv8[db] = *(const bf16x8*)&Vsc[d * 64 + (((kh * 4 + quad) ^ (d & 7))) * 8];
        }
        #pragma unroll
        for (int t = 0; t < 2; ++t) {
            f32x4 sv0 = {0.f, 0.f, 0.f, 0.f};
            f32x4 sv1 = {0.f, 0.f, 0.f, 0.f};
            __builtin_amdgcn_s_setprio(1);
            sv0 = __builtin_amdgcn_mfma_f32_16x16x32_bf16(kA[0][0], aq[t][0], sv0, 0, 0, 0);
            sv0 = __builtin_amdgcn_mfma_f32_16x16x32_bf16(kA[0][1], aq[t][1], sv0, 0, 0, 0);
            sv1 = __builtin_amdgcn_mfma_f32_16x16x32_bf16(kA[1][0], aq[t][0], sv1, 0, 0, 0);
            sv1 = __builtin_amdgcn_mfma_f32_16x16x32_bf16(kA[1][1], aq[t][1], sv1, 0, 0, 0);
            __builtin_amdgcn_s_setprio(0);
            float p0 = __builtin_amdgcn_exp2f(sv0[0]);
            float p1 = __builtin_amdgcn_exp2f(sv0[1]);
            float p2 = __builtin_amdgcn_exp2f(sv0[2]);
            float p3 = __builtin_amdgcn_exp2f(sv0[3]);
            float p4 = __builtin_amdgcn_exp2f(sv1[0]);
            float p5 = __builtin_amdgcn_exp2f(sv1[1]);
            float p6 = __builtin_amdgcn_exp2f(sv1[2]);
            float p7 = __builtin_amdgcn_exp2f(sv1[3]);
            lp[t] += ((p0 + p1) + (p2 + p3)) + ((p4 + p5) + (p6 + p7));
            union { unsigned int u[4]; bf16x8 v; } ap;
            ap.u[0] = pack_bf16_trunc(p0, p1);
            ap.u[1] = pack_bf16_trunc(p2, p3);
            ap.u[2] = pack_bf16_trunc(p4, p5);
            ap.u[3] = pack_bf16_trunc(p6, p7);
            __builtin_amdgcn_s_setprio(1);
            #pragma unroll
            for (int db = 0; db < 4; ++db)
                o[t][db] = __builtin_amdgcn_mfma_f32_16x16x32_bf16(ap.v, bv8[db], o[t][db], 0, 0, 0);
            __builtin_amdgcn_s_setprio(0);
        }
        __builtin_amdgcn_sched_barrier(0);
    }
#undef STAGE

    // ---- epilogue: l over quads (shfl); O/l over kh pairs via LDS; write bf16.
    __syncthreads();
    #pragma unroll
    for (int t = 0; t < 2; ++t) {
        float v = lp[t];
        v += __shfl_xor(v, 16, 64);
        v += __shfl_xor(v, 32, 64);
        if (quad == 0) Lred[(wave * 2 + t) * 16 + l15] = v;
    }
    __syncthreads();
    float* myO = Ored + wave * (16 * 64);
    #pragma unroll
    for (int t = 0; t < 2; ++t) {
        #pragma unroll
        for (int db = 0; db < 4; ++db)
            #pragma unroll
            for (int r = 0; r < 4; ++r)
                myO[(quad * 4 + r) * 64 + db * 16 + l15] = o[t][db][r];
        __syncthreads();
        {
            int q_l = tid >> 3;              // 0..31
            int dg = tid & 7;
            int qh2 = q_l >> 4, qq = q_l & 15;
            const float* r0p = Ored + (qh2 * 2 + 0) * (16 * 64) + qq * 64 + dg * 8;
            const float* r1p = Ored + (qh2 * 2 + 1) * (16 * 64) + qq * 64 + dg * 8;
            float4 a0 = *(const float4*)&r0p[0];
            float4 a1 = *(const float4*)&r0p[4];
            float4 c0 = *(const float4*)&r1p[0];
            float4 c1 = *(const float4*)&r1p[4];
            float lt = Lred[((qh2 * 2 + 0) * 2 + t) * 16 + qq] +
                       Lred[((qh2 * 2 + 1) * 2 + t) * 16 + qq];
            float inv = 1.f / lt;
            size_t row = qrow0 + qh2 * 32 + t * 16 + qq;
            unsigned short* dst = &Ab[row * EMB + h * 64 + dg * 8];
            ushort4 lo = { f_to_bf16((a0.x + c0.x) * inv), f_to_bf16((a0.y + c0.y) * inv),
                           f_to_bf16((a0.z + c0.z) * inv), f_to_bf16((a0.w + c0.w) * inv) };
            ushort4 hi = { f_to_bf16((a1.x + c1.x) * inv), f_to_bf16((a1.y + c1.y) * inv),
                           f_to_bf16((a1.z + c1.z) * inv), f_to_bf16((a1.w + c1.w) * inv) };
            *(ushort4*)&dst[0] = lo;
            *(ushort4*)&dst[4] = hi;
        }
        __syncthreads();
    }
}

// ---- y = x + P; LayerNorm -> out. 4 rows per block (1 wave each).
__global__ __launch_bounds__(256) void ln_kernel(
        const float* __restrict__ xf, const unsigned short* __restrict__ xraw,
        const unsigned short* __restrict__ P,
        const float* __restrict__ gamma, const float* __restrict__ beta,
        void* __restrict__ out) {
    int fp32 = detect_fp32(xraw);
    int row = blockIdx.x * 4 + (threadIdx.x >> 6);
    int t = threadIdx.x & 63;
    float v[8];
    float s = 0.f, ss = 0.f;
    const unsigned short* pp = &P[(size_t)row * EMB + t * 8];
    ushort4 p0 = *(const ushort4*)&pp[0];
    ushort4 p1 = *(const ushort4*)&pp[4];
    float pv[8] = { bf16_to_f(p0.x), bf16_to_f(p0.y), bf16_to_f(p0.z), bf16_to_f(p0.w),
                    bf16_to_f(p1.x), bf16_to_f(p1.y), bf16_to_f(p1.z), bf16_to_f(p1.w) };
    if (fp32) {
        const float* xp = &xf[(size_t)row * EMB + t * 8];
        for (int i = 0; i < 8; i += 4) {
            float4 x4 = *(const float4*)&xp[i];
            v[i] = x4.x + pv[i]; v[i+1] = x4.y + pv[i+1];
            v[i+2] = x4.z + pv[i+2]; v[i+3] = x4.w + pv[i+3];
        }
    } else {
        const unsigned short* xp = &xraw[(size_t)row * EMB + t * 8];
        ushort4 x0 = *(const ushort4*)&xp[0];
        ushort4 x1 = *(const ushort4*)&xp[4];
        v[0] = bf16_to_f(x0.x) + pv[0]; v[1] = bf16_to_f(x0.y) + pv[1];
        v[2] = bf16_to_f(x0.z) + pv[2]; v[3] = bf16_to_f(x0.w) + pv[3];
        v[4] = bf16_to_f(x1.x) + pv[4]; v[5] = bf16_to_f(x1.y) + pv[5];
        v[6] = bf16_to_f(x1.z) + pv[6]; v[7] = bf16_to_f(x1.w) + pv[7];
    }
    for (int i = 0; i < 8; ++i) { s += v[i]; ss += v[i] * v[i]; }
    for (int off = 32; off > 0; off >>= 1) {
        s  += __shfl_xor(s, off, 64);
        ss += __shfl_xor(ss, off, 64);
    }
    float mu = s * (1.f / 512.f);
    float var = ss * (1.f / 512.f) - mu * mu;
    float rs = rsqrtf(var + 1e-5f);
    for (int i = 0; i < 8; ++i) {
        int col = t * 8 + i;
        float y = (v[i] - mu) * rs * gamma[col] + beta[col];
        if (fp32) ((float*)out)[(size_t)row * EMB + col] = y;
        else      ((__hip_bfloat16*)out)[(size_t)row * EMB + col] = __float2bfloat16(y);
    }
}

extern "C" void kernel_launch(void* const* d_in, const int* in_sizes, int n_in,
                              void* d_out, int out_size, void* d_ws, size_t ws_size,
                              hipStream_t stream) {
    char* ws = (char*)d_ws;
    char* p = ws + 256;
    float* bias_all = (float*)p;       p += 6 * 512 * 4;
    unsigned short* Wt   = (unsigned short*)p; p += (size_t)2048 * 512 * 2;  // 2MB
    unsigned short* QKVb = (unsigned short*)p; p += (size_t)ROWS * 1536 * 2; // 24MB
    unsigned short* Vt   = (unsigned short*)p; p += (size_t)16 * HD * SEQ * 2; // 8MB
    // shared region: xb (prep -> QKV gemm) then Ab (attn -> O-proj)
    unsigned short* xb = (unsigned short*)p;
    unsigned short* Ab = (unsigned short*)p;   p += (size_t)ROWS * EMB * 2;  // 8MB
    unsigned short* Pb = (unsigned short*)p;   p += (size_t)ROWS * EMB * 2;  // 8MB

    prep_kernel<<<4364, 256, 0, stream>>>(d_in[0], xb,
        d_in[1], d_in[3], d_in[5], d_in[7], Wt,
        d_in[2], d_in[4], d_in[6], d_in[8], d_in[9], d_in[10], bias_all);

    // fused QKV: N=1536; Q cols pre-scaled by QSCALE; V cols written transposed to Vt
    gemm_mfma_kernel<unsigned short><<<dim3(12, 64), 256, 0, stream>>>(
        xb, (const unsigned short*)d_in[0], Wt, bias_all, QKVb, 1536, 512, Vt);

    attn_kernel<<<dim3(1024), 256, 0, stream>>>(QKVb, Vt, Ab);

    // O-proj -> bf16
    gemm_mfma_kernel<unsigned short><<<dim3(4, 64), 256, 0, stream>>>(
        Ab, Ab, Wt + (size_t)1536 * 512, bias_all + 1536, Pb, 512, 0,
        (unsigned short*)nullptr);

    ln_kernel<<<ROWS / 4, 256, 0, stream>>>((const float*)d_in[0],
                                            (const unsigned short*)d_in[0], Pb,
                                            bias_all + 4 * 512, bias_all + 5 * 512, d_out);
}